// Round 8
// baseline (1004.972 us; speedup 1.0000x reference)
//
#include <hip/hip_runtime.h>
#include <hip/hip_bf16.h>

typedef unsigned short u16;
typedef __attribute__((ext_vector_type(8))) short bfrag;   // 8 bf16 = 4 VGPR
typedef __attribute__((ext_vector_type(4))) float f32x4;
typedef __attribute__((ext_vector_type(2))) int i32x2;
typedef __attribute__((ext_vector_type(4))) int i32x4;

// ---------------- ws float-offset layout ----------------
constexpr int OFF_N1G  = 64;                    // int flag at float[0]
constexpr int OFF_N1B  = OFF_N1G + 256;         // 320
constexpr int OFF_QKVB = OFF_N1B + 256;         // 576  (768)
constexpr int OFF_PB   = OFF_QKVB + 768;        // 1344 (256)
constexpr int OFF_N2G  = OFF_PB + 256;          // 1600
constexpr int OFF_N2B  = OFF_N2G + 256;         // 1856
constexpr int OFF_F1B  = OFF_N2B + 256;         // 2112 (1024)
constexpr int OFF_F2B  = OFF_F1B + 1024;        // 3136 (256)
constexpr int OFF_BIAS = OFF_F2B + 256;         // 3392  (+65536 -> 68928)
constexpr int OFF_QWT  = OFF_BIAS + 65536;      // 68928 (+49152 -> 118080)
constexpr int OFF_PWT  = OFF_QWT + 49152;       // 118080 (+16384 -> 134464)
constexpr int OFF_F1WT = OFF_PWT + 16384;       // 134464 (+65536 -> 200000)
constexpr int OFF_F2WT = OFF_F1WT + 65536;      // 200000 (+65536 -> 265536)
constexpr long OFF_XBUF = 265728;               // 256-aligned
constexpr long OFF_IBUF = OFF_XBUF + 33554432;  // xbuf = 33.55M floats; ibuf = 33.55M u16

__device__ __forceinline__ float blo(unsigned w) { return __uint_as_float(w << 16); }
__device__ __forceinline__ u16 f2b(float f) {
  unsigned u = __float_as_uint(f);
  u += 0x7fffu + ((u >> 16) & 1u);
  return (u16)(u >> 16);
}
// packed RNE f32x2 -> bf16x2 (lo = a, hi = b)
__device__ __forceinline__ unsigned f2b_pk(float a, float b) {
  unsigned r;
  asm("v_cvt_pk_bf16_f32 %0, %1, %2" : "=v"(r) : "v"(a), "v"(b));
  return r;
}
__device__ __forceinline__ float ldin(const void* p, long i, int bf) {
  if (bf) return blo((unsigned)((const u16*)p)[i]);
  return ((const float*)p)[i];
}
__device__ __forceinline__ f32x4 mfma16(bfrag a, bfrag b, f32x4 c) {
  return __builtin_amdgcn_mfma_f32_16x16x32_bf16(a, b, c, 0, 0, 0);
}
// GELU with Abramowitz-Stegun 7.1.26 erf (|err| <= 1.5e-7, far below bf16 ulp)
__device__ __forceinline__ float fast_gelu(float x) {
  const float z = fabsf(x) * 0.70710678118f;
  const float tt = __builtin_amdgcn_rcpf(1.0f + 0.3275911f * z);
  const float poly = tt * (0.254829592f + tt * (-0.284496736f + tt * (1.421413741f +
                     tt * (-1.453152027f + tt * 1.061405429f))));
  const float erfz = 1.0f - poly * __expf(-z * z);
  return x * 0.5f * (1.0f + copysignf(erfz, x));
}

// ---------------- dtype sniff ----------------
__global__ void k_sniff(const u16* __restrict__ x, int* __restrict__ flag) {
  __shared__ int sc[4];
  const int t = threadIdx.x;
  int c = 0;
  for (int i = t; i < 4096; i += 256) {
    const int e = (x[2 * i] >> 7) & 0xFF;
    c += (e >= 96 && e <= 143) ? 1 : 0;
  }
  #pragma unroll
  for (int o = 32; o; o >>= 1) c += __shfl_down(c, o);
  if ((t & 63) == 0) sc[t >> 6] = c;
  __syncthreads();
  if (t == 0) *flag = ((sc[0] + sc[1] + sc[2] + sc[3]) > 2400) ? 1 : 0;
}

// ---------------- small f32 param convert ----------------
__global__ void k_convert(const void* __restrict__ src, float* __restrict__ dst, int n,
                          const int* __restrict__ flagp) {
  const int bf = *flagp;
  const int i = blockIdx.x * 256 + threadIdx.x;
  if (i < n) dst[i] = ldin(src, i, bf);
}

// ---------------- transposed bf16 weight convert: dst[l][n][k] = src[l][k][n] ----------------
__global__ void k_cvtT(const void* __restrict__ src, u16* __restrict__ dst, int K, int N,
                       const int* __restrict__ flagp) {
  const int bf = *flagp;
  const int id = blockIdx.x * 256 + threadIdx.x;
  const int KN = K * N;
  if (id >= 2 * KN) return;
  const int l = id / KN, r = id % KN;
  const int n = r % N, k = r / N;
  const float v = ldin(src, (long)l * KN + (long)k * N + n, bf);
  dst[((long)l * N + n) * K + k] = f2b(v);
}

// ---------------- FFN weight converts: 16KB-tile-contiguous + XOR-pre-swizzled ----------------
// f1: src [l][k=128][n=512] -> tile (n>>6): [64 cols][128 k], idx^((n&7)<<3)
__global__ void k_cvtF1(const void* __restrict__ src, u16* __restrict__ dst,
                        const int* __restrict__ flagp) {
  const int bf = *flagp;
  const int id = blockIdx.x * 256 + threadIdx.x;   // 2*65536
  const int l = id >> 16, r = id & 65535;
  const int k = r >> 9, n = r & 511;
  const float v = ldin(src, (long)l * 65536 + k * 512 + n, bf);
  dst[(long)l * 65536 + (n >> 6) * 8192 + (((n & 63) * 128 + k) ^ ((n & 7) << 3))] = f2b(v);
}
// f2: src [l][k=512][n=128] -> tile (k>>6): [128 cols][64 k], idx^((n&7)<<3)
__global__ void k_cvtF2(const void* __restrict__ src, u16* __restrict__ dst,
                        const int* __restrict__ flagp) {
  const int bf = *flagp;
  const int id = blockIdx.x * 256 + threadIdx.x;   // 2*65536
  const int l = id >> 16, r = id & 65535;
  const int k = r >> 7, n = r & 127;
  const float v = ldin(src, (long)l * 65536 + k * 128 + n, bf);
  dst[(long)l * 65536 + (k >> 6) * 8192 + ((n * 64 + (k & 63)) ^ ((n & 7) << 3))] = f2b(v);
}

// ---------------- relative-position bias table: TRANSPOSED [l][h][j][i] ----------------
__global__ void k_bias(const void* __restrict__ tbl, float* __restrict__ dst,
                       const int* __restrict__ flagp) {
  const int bf = *flagp;
  const int id = blockIdx.x * 256 + threadIdx.x;  // 2*8*64*64
  const int j = id & 63, i = (id >> 6) & 63;
  const int idx = ((i >> 3) - (j >> 3) + 7) * 15 + ((i & 7) - (j & 7) + 7);
  const int h = (id >> 12) & 7, l = id >> 15;
  dst[(id & ~4095) + j * 64 + i] = ldin(tbl, (long)l * 1800 + idx * 8 + h, bf);
}

// ---------------- x: (B,C,H,W) -> (B,H,W,C) f32  AND  illu -> (B,H,W,C) bf16 ----------------
__global__ __launch_bounds__(256) void k_tin(const void* __restrict__ src,
                                             const void* __restrict__ il,
                                             float* __restrict__ dst,
                                             u16* __restrict__ idst,
                                             const int* __restrict__ flagp) {
  __shared__ float tile[64][65];
  const int bf = *flagp;
  const int bid = blockIdx.x;     // B*H*4*2 = 8192
  const int cb = bid & 1, wb = (bid >> 1) & 3, h = (bid >> 3) & 255, b = bid >> 11;
  const int tw = threadIdx.x & 63, tg = threadIdx.x >> 6;
  #pragma unroll
  for (int i = 0; i < 16; ++i) {
    const int c = i * 4 + tg;
    tile[c][tw] = ldin(src, ((long)((b * 128 + cb * 64 + c) * 256 + h)) * 256 + wb * 64 + tw, bf);
  }
  __syncthreads();
  #pragma unroll
  for (int i = 0; i < 16; ++i) {
    const int wl = i * 4 + tg;
    const int pix = (b * 256 + h) * 256 + wb * 64 + wl;
    dst[(size_t)pix * 128 + cb * 64 + tw] = tile[tw][wl];
  }
  __syncthreads();
  #pragma unroll
  for (int i = 0; i < 16; ++i) {
    const int c = i * 4 + tg;
    tile[c][tw] = ldin(il, ((long)((b * 128 + cb * 64 + c) * 256 + h)) * 256 + wb * 64 + tw, bf);
  }
  __syncthreads();
  #pragma unroll
  for (int i = 0; i < 16; ++i) {
    const int wl = i * 4 + tg;
    const int pix = (b * 256 + h) * 256 + wb * 64 + wl;
    idst[(size_t)pix * 128 + cb * 64 + tw] = f2b(tile[tw][wl]);
  }
}

// xn swizzled address: token row of 128 bf16, 16B chunks XOR'd by token
__device__ __forceinline__ int xn_addr(int tok, int chunk) {
  return tok * 128 + ((chunk ^ (tok & 7)) << 3);
}

// ---------------- fused LN1 + qkv + attention + proj + residual (whole window) --------------
// grid 4096 windows, 512 threads = 8 waves = 8 heads.
// LDS 48KB via tight overlays: xn(->O after barrier) | QV (V stage -> vb regs -> Q2)
// | K2 (-> kf regs -> P scratch). 3 blocks/CU by LDS; (512,6) caps total regs at 85
// so 6 waves/SIMD (24/CU) fit. s_setprio(1) around MFMA clusters (T5: 3 desynced
// blocks/CU). Tripwire: WRITE_SIZE >> 150MB means the 85-cap spilled -> revert.
__global__ __launch_bounds__(512, 6) void k_attnP(
    float* xbuf, const u16* __restrict__ ibuf,
    const float* __restrict__ wsf,
    const u16* __restrict__ qwT, const u16* __restrict__ pwT,
    const float* __restrict__ biasb, const int blk, const int shift)
{
  __shared__ __align__(16) u16 smem[24576];       // 49152 B
  u16* xn = smem;                  // [64][128] swizzled bf16 (live through GEMMs)
  u16* QV = smem + 8192;           // per-wave w*1024: V staging, then Q2
  u16* K2 = smem + 16384;          // per-wave w*1024: K2, then P scratch
  u16* O  = smem;                  // overlays xn after the post-GEMM barrier

  const int t = threadIdx.x, l = t & 63, w = t >> 6;   // w = head = 0..7
  const int win = blockIdx.x;
  const int b = win >> 10, wh = (win >> 5) & 31, wn = win & 31;
  const int g = l >> 4, c16 = l & 15, c8 = c16 * 8;

  const float* g1 = wsf + OFF_N1G + blk * 128;
  const float* b1 = wsf + OFF_N1B + blk * 128;
  const float* qb = wsf + OFF_QKVB + blk * 384;
  const u16* qwl = qwT + (size_t)blk * 49152;

  // ---- illu prefetch for head w (coalesced 16-lane u16 runs)
  float iw[4][4];
  {
    const u16* ip = ibuf + (size_t)b * 8388608 + w * 16 + c16;
    #pragma unroll
    for (int rt = 0; rt < 4; ++rt)
      #pragma unroll
      for (int r = 0; r < 4; ++r) {
        const int tok = rt * 16 + g * 4 + r;
        const int hh = (wh * 8 + (tok >> 3) + shift) & 255;
        const int wp = (wn * 8 + (tok & 7) + shift) & 255;
        iw[rt][r] = blo(ip[(size_t)((hh << 8) + wp) * 128]);
      }
  }

  // ---- phase 0: LN1, 8 tokens per wave (once per window)
  {
    float gg[8], bb[8];
    *(float4*)&gg[0] = *(const float4*)(g1 + c8);
    *(float4*)&gg[4] = *(const float4*)(g1 + c8 + 4);
    *(float4*)&bb[0] = *(const float4*)(b1 + c8);
    *(float4*)&bb[4] = *(const float4*)(b1 + c8 + 4);
    #pragma unroll
    for (int s = 0; s < 2; ++s) {
      const int tok = w * 8 + s * 4 + g;
      const int hh = (wh * 8 + (tok >> 3) + shift) & 255;
      const int wp = (wn * 8 + (tok & 7) + shift) & 255;
      const float* xr = xbuf + (size_t)((b * 256 + hh) * 256 + wp) * 128 + c8;
      float v[8];
      *(float4*)&v[0] = *(const float4*)xr;
      *(float4*)&v[4] = *(const float4*)(xr + 4);
      float sm = 0.f, sq = 0.f;
      #pragma unroll
      for (int j = 0; j < 8; ++j) { sm += v[j]; sq = fmaf(v[j], v[j], sq); }
      #pragma unroll
      for (int o = 8; o; o >>= 1) { sm += __shfl_xor(sm, o); sq += __shfl_xor(sq, o); }
      const float mean = sm * 0.0078125f;
      const float rstd = rsqrtf(fmaf(-mean, mean, sq * 0.0078125f) + 1e-5f);
      unsigned pk[4];
      #pragma unroll
      for (int jj = 0; jj < 4; ++jj) {
        const float o0 = (v[2 * jj] - mean) * rstd * gg[2 * jj] + bb[2 * jj];
        const float o1 = (v[2 * jj + 1] - mean) * rstd * gg[2 * jj + 1] + bb[2 * jj + 1];
        pk[jj] = f2b_pk(o0, o1);
      }
      i32x4 st; st[0] = (int)pk[0]; st[1] = (int)pk[1]; st[2] = (int)pk[2]; st[3] = (int)pk[3];
      *(i32x4*)&xn[(tok * 128 + c8) ^ ((tok & 7) << 3)] = st;
    }
  }
  __syncthreads();

  // ---- phase 1a: V GEMM (frees iw), modulate, stage to own QV chunk, read vb
  bfrag vb[2];
  {
    const int colv = (16 + w) * 16 + c16;
    const float bv = qb[colv];
    f32x4 acv[4];
    #pragma unroll
    for (int rt = 0; rt < 4; ++rt) acv[rt] = (f32x4){bv, bv, bv, bv};
    const u16* bp = qwl + colv * 128 + g * 8;
    __builtin_amdgcn_s_setprio(1);
    #pragma unroll
    for (int kt = 0; kt < 4; ++kt) {
      const bfrag bw = *(const bfrag*)(bp + kt * 32);
      #pragma unroll
      for (int rt = 0; rt < 4; ++rt) {
        const bfrag a = *(const bfrag*)&xn[xn_addr(rt * 16 + c16, kt * 4 + g)];
        acv[rt] = mfma16(a, bw, acv[rt]);
      }
    }
    __builtin_amdgcn_s_setprio(0);
    u16* vt = QV + w * 1024 + c16 * 64;
    const int sx = (c16 & 7) << 3;
    #pragma unroll
    for (int rt = 0; rt < 4; ++rt) {
      const unsigned p0 = f2b_pk(acv[rt][0] * iw[rt][0], acv[rt][1] * iw[rt][1]);
      const unsigned p1 = f2b_pk(acv[rt][2] * iw[rt][2], acv[rt][3] * iw[rt][3]);
      i32x2 pp; pp[0] = (int)p0; pp[1] = (int)p1;
      *(i32x2*)&vt[(rt * 16 + g * 4) ^ sx] = pp;
    }
    // own-wave readback (compiler orders LDS ops on aliasing pointers)
    #pragma unroll
    for (int kt = 0; kt < 2; ++kt)
      vb[kt] = *(const bfrag*)&QV[w * 1024 + c16 * 64 + ((kt * 32 + g * 8) ^ sx)];
  }

  // ---- phase 1b: Q GEMM -> own QV chunk (overwrites V staging; vb already in regs)
  {
    const int colq = w * 16 + c16;
    const float bq = qb[colq];
    f32x4 acq[4];
    #pragma unroll
    for (int rt = 0; rt < 4; ++rt) acq[rt] = (f32x4){bq, bq, bq, bq};
    const u16* bpq = qwl + colq * 128 + g * 8;
    __builtin_amdgcn_s_setprio(1);
    #pragma unroll
    for (int kt = 0; kt < 4; ++kt) {
      const bfrag bwq = *(const bfrag*)(bpq + kt * 32);
      #pragma unroll
      for (int rt = 0; rt < 4; ++rt) {
        const bfrag a = *(const bfrag*)&xn[xn_addr(rt * 16 + c16, kt * 4 + g)];
        acq[rt] = mfma16(a, bwq, acq[rt]);
      }
    }
    __builtin_amdgcn_s_setprio(0);
    u16* dq = QV + w * 1024 + ((c16 >> 3) * 64) * 8 + (c16 & 7);
    #pragma unroll
    for (int rt = 0; rt < 4; ++rt)
      #pragma unroll
      for (int r = 0; r < 4; ++r)
        dq[(rt * 16 + g * 4 + r) * 8] = f2b(acq[rt][r]);
  }

  // ---- phase 1c: K GEMM -> own K2 chunk, read kf
  const bfrag zfrag = {0, 0, 0, 0, 0, 0, 0, 0};
  const f32x4 zacc = {0.f, 0.f, 0.f, 0.f};
  bfrag kf[4];
  {
    const int colk = 128 + w * 16 + c16;
    const float bk = qb[colk];
    f32x4 ack[4];
    #pragma unroll
    for (int rt = 0; rt < 4; ++rt) ack[rt] = (f32x4){bk, bk, bk, bk};
    const u16* bpk = qwl + colk * 128 + g * 8;
    __builtin_amdgcn_s_setprio(1);
    #pragma unroll
    for (int kt = 0; kt < 4; ++kt) {
      const bfrag bwk = *(const bfrag*)(bpk + kt * 32);
      #pragma unroll
      for (int rt = 0; rt < 4; ++rt) {
        const bfrag a = *(const bfrag*)&xn[xn_addr(rt * 16 + c16, kt * 4 + g)];
        ack[rt] = mfma16(a, bwk, ack[rt]);
      }
    }
    __builtin_amdgcn_s_setprio(0);
    u16* dk = K2 + w * 1024 + ((c16 >> 3) * 64) * 8 + (c16 & 7);
    #pragma unroll
    for (int rt = 0; rt < 4; ++rt)
      #pragma unroll
      for (int r = 0; r < 4; ++r)
        dk[(rt * 16 + g * 4 + r) * 8] = f2b(ack[rt][r]);
    #pragma unroll
    for (int jt = 0; jt < 4; ++jt) {
      bfrag v = zfrag;
      if (l < 32) v = *(const bfrag*)&K2[w * 1024 + (g * 64 + jt * 16 + c16) * 8];
      kf[jt] = v;
    }
  }
  __syncthreads();   // all xn reads done; xn region may now become O

  // ---- phases 2+3 fused per 16-row block: S -> softmax -> PV -> O(LDS)
  const float* bl2 = biasb + blk * 32768 + w * 4096;
  const bool mk = (shift > 0) && ((wh == 31) || (wn == 31));
  int lj[4];
  if (mk) {
    #pragma unroll
    for (int jt = 0; jt < 4; ++jt) {
      const int j = jt * 16 + c16;
      lj[jt] = ((wh == 31) ? (((j >> 3) < 4) ? 1 : 2) : 0) * 3 +
               ((wn == 31) ? (((j & 7) < 4) ? 1 : 2) : 0);
    }
  }
  u16* Pw = K2 + w * 1024;   // kf in regs (all waves, pre-barrier); K2 becomes P scratch

  #pragma unroll
  for (int it = 0; it < 4; ++it) {
    bfrag qf = zfrag;
    if (l < 32) qf = *(const bfrag*)&QV[w * 1024 + (g * 64 + it * 16 + c16) * 8];
    f32x4 s4[4];
    __builtin_amdgcn_s_setprio(1);
    #pragma unroll
    for (int jt = 0; jt < 4; ++jt) s4[jt] = mfma16(qf, kf[jt], zacc);
    __builtin_amdgcn_s_setprio(0);

    #pragma unroll
    for (int jt = 0; jt < 4; ++jt) {
      const float4 bv4 = *(const float4*)&bl2[(jt * 16 + c16) * 64 + it * 16 + g * 4];
      #pragma unroll
      for (int r = 0; r < 4; ++r)
        s4[jt][r] = fmaf(s4[jt][r], 0.25f, (&bv4.x)[r]);
    }
    if (mk) {
      #pragma unroll
      for (int r = 0; r < 4; ++r) {
        const int i = it * 16 + g * 4 + r;
        const int li = ((wh == 31) ? (((i >> 3) < 4) ? 1 : 2) : 0) * 3 +
                       ((wn == 31) ? (((i & 7) < 4) ? 1 : 2) : 0);
        #pragma unroll
        for (int jt = 0; jt < 4; ++jt)
          if (li != lj[jt]) s4[jt][r] = -1e30f;
      }
    }

    #pragma unroll
    for (int r = 0; r < 4; ++r) {
      float mx = fmaxf(fmaxf(s4[0][r], s4[1][r]), fmaxf(s4[2][r], s4[3][r]));
      #pragma unroll
      for (int o = 8; o; o >>= 1) mx = fmaxf(mx, __shfl_xor(mx, o));
      float e0 = __expf(s4[0][r] - mx);
      float e1 = __expf(s4[1][r] - mx);
      float e2 = __expf(s4[2][r] - mx);
      float e3 = __expf(s4[3][r] - mx);
      float sm = e0 + e1 + e2 + e3;
      #pragma unroll
      for (int o = 8; o; o >>= 1) sm += __shfl_xor(sm, o);
      const float inv = 1.0f / sm;
      s4[0][r] = e0 * inv; s4[1][r] = e1 * inv;
      s4[2][r] = e2 * inv; s4[3][r] = e3 * inv;
    }

    #pragma unroll
    for (int jt = 0; jt < 4; ++jt)
      #pragma unroll
      for (int r = 0; r < 4; ++r)
        Pw[(g * 4 + r) * 40 + jt * 16 + c16] = f2b(s4[jt][r]);
    const bfrag pa0 = *(const bfrag*)&Pw[c16 * 40 + g * 8];
    const bfrag pa1 = *(const bfrag*)&Pw[c16 * 40 + 32 + g * 8];
    f32x4 o = zacc;
    __builtin_amdgcn_s_setprio(1);
    o = mfma16(pa0, vb[0], o);
    o = mfma16(pa1, vb[1], o);
    __builtin_amdgcn_s_setprio(0);
    // O[tok][col] swizzled like xn; col = w*16 + c16
    #pragma unroll
    for (int r = 0; r < 4; ++r) {
      const int tok = it * 16 + g * 4 + r;
      O[tok * 128 + (((w * 2 + (c16 >> 3)) ^ (tok & 7)) << 3) + (c16 & 7)] = f2b(o[r]);
    }
  }
  __syncthreads();   // O fully staged

  // ---- phase 4: proj GEMM + residual. wave w: row-tile (w&3), col-half (w>>2)
  {
    const int prt = w & 3, ph = w >> 2;
    bfrag af[4];
    #pragma unroll
    for (int kt = 0; kt < 4; ++kt)
      af[kt] = *(const bfrag*)&O[xn_addr(prt * 16 + c16, kt * 4 + g)];
    const u16* pwl = pwT + blk * 16384;
    const float* pb = wsf + OFF_PB + blk * 128;
    #pragma unroll
    for (int ct = 0; ct < 4; ++ct) {
      const int col = ph * 64 + ct * 16 + c16;
      const float bv = pb[col];
      f32x4 ac = {bv, bv, bv, bv};
      const u16* bp = pwl + col * 128 + g * 8;
      __builtin_amdgcn_s_setprio(1);
      #pragma unroll
      for (int kt = 0; kt < 4; ++kt) ac = mfma16(af[kt], *(const bfrag*)(bp + kt * 32), ac);
      __builtin_amdgcn_s_setprio(0);
      #pragma unroll
      for (int r = 0; r < 4; ++r) {
        const int tok = prt * 16 + g * 4 + r;
        const int hh = (wh * 8 + (tok >> 3) + shift) & 255;
        const int wp = (wn * 8 + (tok & 7) + shift) & 255;
        const size_t xi = (size_t)((b * 256 + hh) * 256 + wp) * 128 + col;
        xbuf[xi] += ac[r];
      }
    }
  }
}

// ---------------- fused LN2 + FFN v5c: round-2 v5 + (256,3) reg cap (round-6 verified) ----
__global__ __launch_bounds__(256, 3) void k_ffn(
    float* xbuf, const float* __restrict__ wsf,
    const u16* __restrict__ f1S, const u16* __restrict__ f2S,
    const int blk, void* __restrict__ outp, const int last,
    const int* __restrict__ flagp)
{
  __shared__ __align__(16) u16 B0[8192];    // 16KB weight tile buf (ping)
  __shared__ __align__(16) u16 B1[8192];    // 16KB weight tile buf (pong)
  __shared__ __align__(16) u16 hid[8192];   // 16KB: 4 waves x [16 rows][128] XOR-swz
  __shared__ float sbias[512];              // f1 biases (keeps loop VMEM-clean)
  const int bfl = *flagp;
  const int t = threadIdx.x, l = t & 63, w = t >> 6;
  u16* hw = hid + w * 2048;
  const int pix0 = blockIdx.x * 64;
  const float* g2 = wsf + OFF_N2G + blk * 128;
  const float* b2 = wsf + OFF_N2B + blk * 128;
  const float* f1bp = wsf + OFF_F1B + blk * 512;
  const float* f2bp = wsf + OFF_F2B + blk * 128;
  const u16* f1 = f1S + (size_t)blk * 65536;
  const u16* f2 = f2S + (size_t)blk * 65536;

  auto STAGE = [&](const u16* src, u16* dstbuf) {
    const u16* gp = src + w * 2048 + l * 8;
    u16* d = dstbuf + w * 2048;
    #pragma unroll
    for (int q = 0; q < 4; ++q)
      __builtin_amdgcn_global_load_lds(gp + q * 512, d + q * 512, 16, 0, 0);
  };
  auto tsrc = [&](int i) -> const u16* {
    const int cc = i >> 2, pp = i & 3;
    return (pp < 2 ? f1 : f2) + cc * 16384 + (pp & 1) * 8192;
  };

  STAGE(tsrc(0), B0);
  sbias[t] = f1bp[t];
  sbias[t + 256] = f1bp[t + 256];

  {
    const int g = l >> 4, c16 = l & 15, c8 = c16 * 8;
    float gg[8], bb[8];
    *(float4*)&gg[0] = *(const float4*)(g2 + c8);
    *(float4*)&gg[4] = *(const float4*)(g2 + c8 + 4);
    *(float4*)&bb[0] = *(const float4*)(b2 + c8);
    *(float4*)&bb[4] = *(const float4*)(b2 + c8 + 4);
    #pragma unroll
    for (int s = 0; s < 4; ++s) {
      const int tt = s * 4 + g;
      const float* xr = xbuf + (size_t)(pix0 + w * 16 + tt) * 128 + c8;
      float v[8];
      *(float4*)&v[0] = *(const float4*)xr;
      *(float4*)&v[4] = *(const float4*)(xr + 4);
      float sm = 0.f, sq = 0.f;
      #pragma unroll
      for (int j = 0; j < 8; ++j) { sm += v[j]; sq = fmaf(v[j], v[j], sq); }
      #pragma unroll
      for (int o = 8; o; o >>= 1) { sm += __shfl_xor(sm, o); sq += __shfl_xor(sq, o); }
      const float mean = sm * 0.0078125f;
      const float rstd = rsqrtf(fmaf(-mean, mean, sq * 0.0078125f) + 1e-5f);
      unsigned pk[4];
      #pragma unroll
      for (int jj = 0; jj < 4; ++jj) {
        const float o0 = (v[2 * jj] - mean) * rstd * gg[2 * jj] + bb[2 * jj];
        const float o1 = (v[2 * jj + 1] - mean) * rstd * gg[2 * jj + 1] + bb[2 * jj + 1];
        pk[jj] = f2b_pk(o0, o1);
      }
      i32x4 st; st[0] = (int)pk[0]; st[1] = (int)pk[1]; st[2] = (int)pk[2]; st[3] = (int)pk[3];
      *(i32x4*)&hw[(tt * 128 + c8) ^ ((tt & 7) << 3)] = st;
    }
  }
  bfrag af[4];
  #pragma unroll
  for (int kt = 0; kt < 4; ++kt)
    af[kt] = *(const bfrag*)&hw[((l & 15) * 128 + kt * 32 + (l >> 4) * 8) ^ (((l & 15) & 7) << 3)];

  f32x4 y[8];
  #pragma unroll
  for (int ct = 0; ct < 8; ++ct) {
    const float bv = f2bp[ct * 16 + (l & 15)];
    y[ct] = (f32x4){bv, bv, bv, bv};
  }

  for (int c = 0; c < 4; ++c) {
    #pragma unroll
    for (int p = 0; p < 4; ++p) {
      const int i = c * 4 + p;
      if (i < 15) STAGE(tsrc(i + 1), (i & 1) ? B0 : B1);
      if (i == 0) asm volatile("s_waitcnt vmcnt(4) lgkmcnt(0)" ::: "memory");
      else if (i < 15) asm volatile("s_waitcnt vmcnt(4)" ::: "memory");
      else asm volatile("s_waitcnt vmcnt(0)" ::: "memory");
      __builtin_amdgcn_sched_barrier(0);
      __builtin_amdgcn_s_barrier();
      const u16* BUF = (i & 1) ? B1 : B0;
      if (p < 2) {
        #pragma unroll
        for (int c1 = 0; c1 < 4; ++c1) {
          const int wcol = c1 * 16 + (l & 15);
          const int n = p * 64 + wcol;
          const float bv = sbias[c * 128 + n];
          f32x4 a1 = {bv, bv, bv, bv};
          #pragma unroll
          for (int kt = 0; kt < 4; ++kt) {
            const bfrag bw = *(const bfrag*)&BUF[(wcol * 128 + kt * 32 + (l >> 4) * 8) ^ ((wcol & 7) << 3)];
            a1 = mfma16(af[kt], bw, a1);
          }
          #pragma unroll
          for (int r = 0; r < 4; ++r) {
            const int row = (l >> 4) * 4 + r;
            hw[(row * 128 + n) ^ ((row & 7) << 3)] = f2b(fast_gelu(a1[r]));
          }
        }
      } else {
        const int kh = p - 2;
        bfrag a2[2];
        #pragma unroll
        for (int kt = 0; kt < 2; ++kt)
          a2[kt] = *(const bfrag*)&hw[((l & 15) * 128 + kh * 64 + kt * 32 + (l >> 4) * 8) ^ (((l & 15) & 7) << 3)];
        #pragma unroll
        for (int ct = 0; ct < 8; ++ct) {
          const int col = ct * 16 + (l & 15);
          #pragma unroll
          for (int kt = 0; kt < 2; ++kt) {
            const bfrag bw = *(const bfrag*)&BUF[(col * 64 + kt * 32 + (l >> 4) * 8) ^ ((col & 7) << 3)];
            y[ct] = mfma16(a2[kt], bw, y[ct]);
          }
        }
      }
      __builtin_amdgcn_s_barrier();
    }
  }

  #pragma unroll
  for (int ct = 0; ct < 8; ++ct)
    #pragma unroll
    for (int r = 0; r < 4; ++r) {
      const int tok = w * 16 + (l >> 4) * 4 + r;
      const int pix = pix0 + tok;
      const int col = ct * 16 + (l & 15);
      const float rv = xbuf[(size_t)pix * 128 + col] + y[ct][r];
      if (last) {
        const int wp = pix & 255, hh2 = (pix >> 8) & 255, bb = pix >> 16;
        const long oi = (((long)bb * 128 + col) * 256 + hh2) * 256 + wp;
        if (bfl) ((u16*)outp)[oi] = f2b(rv);
        else ((float*)outp)[oi] = rv;
      } else {
        xbuf[(size_t)pix * 128 + col] = rv;
      }
    }
}

extern "C" void kernel_launch(void* const* d_in, const int* in_sizes, int n_in,
                              void* d_out, int out_size, void* d_ws, size_t ws_size,
                              hipStream_t stream) {
  (void)in_sizes; (void)n_in; (void)out_size; (void)ws_size;
  float* wsf = (float*)d_ws;
  int* flag = (int*)d_ws;
  const void* x = d_in[0];
  const void* illu = d_in[1];

  k_sniff<<<1, 256, 0, stream>>>((const u16*)x, flag);

  static const int cv_idx[8] = {2, 3, 5, 8, 9, 10, 12, 14};
  static const int cv_off[8] = {OFF_N1G, OFF_N1B, OFF_QKVB, OFF_PB, OFF_N2G, OFF_N2B, OFF_F1B, OFF_F2B};
  static const int cv_n[8] = {256, 256, 768, 256, 256, 256, 1024, 256};
  for (int i = 0; i < 8; ++i)
    k_convert<<<(cv_n[i] + 255) / 256, 256, 0, stream>>>(d_in[cv_idx[i]], wsf + cv_off[i], cv_n[i], flag);

  u16* qwT = (u16*)(wsf + OFF_QWT);
  u16* pwT = (u16*)(wsf + OFF_PWT);
  u16* f1wS = (u16*)(wsf + OFF_F1WT);
  u16* f2wS = (u16*)(wsf + OFF_F2WT);
  k_cvtT<<<384, 256, 0, stream>>>(d_in[4], qwT, 128, 384, flag);
  k_cvtT<<<128, 256, 0, stream>>>(d_in[7], pwT, 128, 128, flag);
  k_cvtF1<<<512, 256, 0, stream>>>(d_in[11], f1wS, flag);
  k_cvtF2<<<512, 256, 0, stream>>>(d_in[13], f2wS, flag);
  k_bias<<<256, 256, 0, stream>>>(d_in[6], wsf + OFF_BIAS, flag);

  float* xbuf = wsf + OFF_XBUF;
  u16* ibuf = (u16*)(wsf + OFF_IBUF);
  k_tin<<<8192, 256, 0, stream>>>(x, illu, xbuf, ibuf, flag);

  for (int blk = 0; blk < 2; ++blk) {
    const int shift = blk ? 4 : 0;
    k_attnP<<<4096, 512, 0, stream>>>(xbuf, ibuf, wsf, qwT, pwT, wsf + OFF_BIAS, blk, shift);
    k_ffn<<<4096, 256, 0, stream>>>(xbuf, wsf, f1wS, f2wS, blk, d_out, blk == 1 ? 1 : 0, flag);
  }
}

// Round 9
// 988.023 us; speedup vs baseline: 1.0172x; 1.0172x over previous
//
#include <hip/hip_runtime.h>
#include <hip/hip_bf16.h>

typedef unsigned short u16;
typedef __attribute__((ext_vector_type(8))) short bfrag;   // 8 bf16 = 4 VGPR
typedef __attribute__((ext_vector_type(4))) float f32x4;
typedef __attribute__((ext_vector_type(2))) int i32x2;
typedef __attribute__((ext_vector_type(4))) int i32x4;

// ---------------- ws float-offset layout ----------------
constexpr int OFF_N1G  = 64;                    // int flag at float[0]
constexpr int OFF_N1B  = OFF_N1G + 256;         // 320
constexpr int OFF_QKVB = OFF_N1B + 256;         // 576  (768)
constexpr int OFF_PB   = OFF_QKVB + 768;        // 1344 (256)
constexpr int OFF_N2G  = OFF_PB + 256;          // 1600
constexpr int OFF_N2B  = OFF_N2G + 256;         // 1856
constexpr int OFF_F1B  = OFF_N2B + 256;         // 2112 (1024)
constexpr int OFF_F2B  = OFF_F1B + 1024;        // 3136 (256)
constexpr int OFF_BIAS = OFF_F2B + 256;         // 3392  (+65536 -> 68928)
constexpr int OFF_QWT  = OFF_BIAS + 65536;      // 68928 (+49152 -> 118080)
constexpr int OFF_PWT  = OFF_QWT + 49152;       // 118080 (+16384 -> 134464)
constexpr int OFF_F1WT = OFF_PWT + 16384;       // 134464 (+65536 -> 200000)
constexpr int OFF_F2WT = OFF_F1WT + 65536;      // 200000 (+65536 -> 265536)
constexpr long OFF_XBUF = 265728;               // 256-aligned
constexpr long OFF_IBUF = OFF_XBUF + 33554432;  // xbuf = 33.55M floats; ibuf = 33.55M u16

__device__ __forceinline__ float blo(unsigned w) { return __uint_as_float(w << 16); }
__device__ __forceinline__ u16 f2b(float f) {
  unsigned u = __float_as_uint(f);
  u += 0x7fffu + ((u >> 16) & 1u);
  return (u16)(u >> 16);
}
// packed RNE f32x2 -> bf16x2 (lo = a, hi = b)
__device__ __forceinline__ unsigned f2b_pk(float a, float b) {
  unsigned r;
  asm("v_cvt_pk_bf16_f32 %0, %1, %2" : "=v"(r) : "v"(a), "v"(b));
  return r;
}
__device__ __forceinline__ float ldin(const void* p, long i, int bf) {
  if (bf) return blo((unsigned)((const u16*)p)[i]);
  return ((const float*)p)[i];
}
__device__ __forceinline__ f32x4 mfma16(bfrag a, bfrag b, f32x4 c) {
  return __builtin_amdgcn_mfma_f32_16x16x32_bf16(a, b, c, 0, 0, 0);
}
// hid row swizzle: GELU scatter rows {r,4+r,8+r,12+r} need 4 distinct bank-group
// keys. Old ((row&7)<<3) gave rows r and 8+r the SAME key -> 4-way conflicts.
// swr adds bit (row>>3)<<1 -> 4 distinct keys -> <=2-way (free, m136).
__device__ __forceinline__ int swr(int row) {
  return ((row & 7) ^ ((row >> 3) << 1)) << 3;
}
// GELU with Abramowitz-Stegun 7.1.26 erf (|err| <= 1.5e-7, far below bf16 ulp)
__device__ __forceinline__ float fast_gelu(float x) {
  const float z = fabsf(x) * 0.70710678118f;
  const float tt = __builtin_amdgcn_rcpf(1.0f + 0.3275911f * z);
  const float poly = tt * (0.254829592f + tt * (-0.284496736f + tt * (1.421413741f +
                     tt * (-1.453152027f + tt * 1.061405429f))));
  const float erfz = 1.0f - poly * __expf(-z * z);
  return x * 0.5f * (1.0f + copysignf(erfz, x));
}

// ---------------- dtype sniff ----------------
__global__ void k_sniff(const u16* __restrict__ x, int* __restrict__ flag) {
  __shared__ int sc[4];
  const int t = threadIdx.x;
  int c = 0;
  for (int i = t; i < 4096; i += 256) {
    const int e = (x[2 * i] >> 7) & 0xFF;
    c += (e >= 96 && e <= 143) ? 1 : 0;
  }
  #pragma unroll
  for (int o = 32; o; o >>= 1) c += __shfl_down(c, o);
  if ((t & 63) == 0) sc[t >> 6] = c;
  __syncthreads();
  if (t == 0) *flag = ((sc[0] + sc[1] + sc[2] + sc[3]) > 2400) ? 1 : 0;
}

// ---------------- small f32 param convert ----------------
__global__ void k_convert(const void* __restrict__ src, float* __restrict__ dst, int n,
                          const int* __restrict__ flagp) {
  const int bf = *flagp;
  const int i = blockIdx.x * 256 + threadIdx.x;
  if (i < n) dst[i] = ldin(src, i, bf);
}

// ---------------- transposed bf16 weight convert: dst[l][n][k] = src[l][k][n] ----------------
__global__ void k_cvtT(const void* __restrict__ src, u16* __restrict__ dst, int K, int N,
                       const int* __restrict__ flagp) {
  const int bf = *flagp;
  const int id = blockIdx.x * 256 + threadIdx.x;
  const int KN = K * N;
  if (id >= 2 * KN) return;
  const int l = id / KN, r = id % KN;
  const int n = r % N, k = r / N;
  const float v = ldin(src, (long)l * KN + (long)k * N + n, bf);
  dst[((long)l * N + n) * K + k] = f2b(v);
}

// ---------------- FFN weight converts: 16KB-tile-contiguous + XOR-pre-swizzled ----------------
// f1: src [l][k=128][n=512] -> tile (n>>6): [64 cols][128 k], idx^((n&7)<<3)
__global__ void k_cvtF1(const void* __restrict__ src, u16* __restrict__ dst,
                        const int* __restrict__ flagp) {
  const int bf = *flagp;
  const int id = blockIdx.x * 256 + threadIdx.x;   // 2*65536
  const int l = id >> 16, r = id & 65535;
  const int k = r >> 9, n = r & 511;
  const float v = ldin(src, (long)l * 65536 + k * 512 + n, bf);
  dst[(long)l * 65536 + (n >> 6) * 8192 + (((n & 63) * 128 + k) ^ ((n & 7) << 3))] = f2b(v);
}
// f2: src [l][k=512][n=128] -> tile (k>>6): [128 cols][64 k], idx^((n&7)<<3)
__global__ void k_cvtF2(const void* __restrict__ src, u16* __restrict__ dst,
                        const int* __restrict__ flagp) {
  const int bf = *flagp;
  const int id = blockIdx.x * 256 + threadIdx.x;   // 2*65536
  const int l = id >> 16, r = id & 65535;
  const int k = r >> 7, n = r & 127;
  const float v = ldin(src, (long)l * 65536 + k * 128 + n, bf);
  dst[(long)l * 65536 + (k >> 6) * 8192 + ((n * 64 + (k & 63)) ^ ((n & 7) << 3))] = f2b(v);
}

// ---------------- relative-position bias table: TRANSPOSED [l][h][j][i] ----------------
__global__ void k_bias(const void* __restrict__ tbl, float* __restrict__ dst,
                       const int* __restrict__ flagp) {
  const int bf = *flagp;
  const int id = blockIdx.x * 256 + threadIdx.x;  // 2*8*64*64
  const int j = id & 63, i = (id >> 6) & 63;
  const int idx = ((i >> 3) - (j >> 3) + 7) * 15 + ((i & 7) - (j & 7) + 7);
  const int h = (id >> 12) & 7, l = id >> 15;
  dst[(id & ~4095) + j * 64 + i] = ldin(tbl, (long)l * 1800 + idx * 8 + h, bf);
}

// ---------------- x: (B,C,H,W) -> (B,H,W,C) f32  AND  illu -> (B,H,W,C) bf16 ----------------
__global__ __launch_bounds__(256) void k_tin(const void* __restrict__ src,
                                             const void* __restrict__ il,
                                             float* __restrict__ dst,
                                             u16* __restrict__ idst,
                                             const int* __restrict__ flagp) {
  __shared__ float tile[64][65];
  const int bf = *flagp;
  const int bid = blockIdx.x;     // B*H*4*2 = 8192
  const int cb = bid & 1, wb = (bid >> 1) & 3, h = (bid >> 3) & 255, b = bid >> 11;
  const int tw = threadIdx.x & 63, tg = threadIdx.x >> 6;
  #pragma unroll
  for (int i = 0; i < 16; ++i) {
    const int c = i * 4 + tg;
    tile[c][tw] = ldin(src, ((long)((b * 128 + cb * 64 + c) * 256 + h)) * 256 + wb * 64 + tw, bf);
  }
  __syncthreads();
  #pragma unroll
  for (int i = 0; i < 16; ++i) {
    const int wl = i * 4 + tg;
    const int pix = (b * 256 + h) * 256 + wb * 64 + wl;
    dst[(size_t)pix * 128 + cb * 64 + tw] = tile[tw][wl];
  }
  __syncthreads();
  #pragma unroll
  for (int i = 0; i < 16; ++i) {
    const int c = i * 4 + tg;
    tile[c][tw] = ldin(il, ((long)((b * 128 + cb * 64 + c) * 256 + h)) * 256 + wb * 64 + tw, bf);
  }
  __syncthreads();
  #pragma unroll
  for (int i = 0; i < 16; ++i) {
    const int wl = i * 4 + tg;
    const int pix = (b * 256 + h) * 256 + wb * 64 + wl;
    idst[(size_t)pix * 128 + cb * 64 + tw] = f2b(tile[tw][wl]);
  }
}

// xn swizzled address: token row of 128 bf16, 16B chunks XOR'd by token
__device__ __forceinline__ int xn_addr(int tok, int chunk) {
  return tok * 128 + ((chunk ^ (tok & 7)) << 3);
}

// ---------------- fused LN1 + qkv + attention + proj + residual (whole window) --------------
// grid 4096 windows, 512 threads = 8 waves = 8 heads.
// LDS 48KB via tight overlays: xn(->O after barrier) | QV (V stage -> vb regs -> Q2)
// | K2 (-> kf regs -> P scratch).
// (512,4): round-8 lesson — (512,6)'s 85-total-reg cap spilled (~130MB scratch,
// VGPR 40, WRITE 195MB). Live set ~92-100 total fits the 128 cap with zero spill;
// 2 blocks/CU (16 waves) is this structure's register-imposed residency ceiling.
__global__ __launch_bounds__(512, 4) void k_attnP(
    float* xbuf, const u16* __restrict__ ibuf,
    const float* __restrict__ wsf,
    const u16* __restrict__ qwT, const u16* __restrict__ pwT,
    const float* __restrict__ biasb, const int blk, const int shift)
{
  __shared__ __align__(16) u16 smem[24576];       // 49152 B
  u16* xn = smem;                  // [64][128] swizzled bf16 (live through GEMMs)
  u16* QV = smem + 8192;           // per-wave w*1024: V staging, then Q2
  u16* K2 = smem + 16384;          // per-wave w*1024: K2, then P scratch
  u16* O  = smem;                  // overlays xn after the post-GEMM barrier

  const int t = threadIdx.x, l = t & 63, w = t >> 6;   // w = head = 0..7
  const int win = blockIdx.x;
  const int b = win >> 10, wh = (win >> 5) & 31, wn = win & 31;
  const int g = l >> 4, c16 = l & 15, c8 = c16 * 8;

  const float* g1 = wsf + OFF_N1G + blk * 128;
  const float* b1 = wsf + OFF_N1B + blk * 128;
  const float* qb = wsf + OFF_QKVB + blk * 384;
  const u16* qwl = qwT + (size_t)blk * 49152;

  // ---- illu prefetch for head w (coalesced 16-lane u16 runs)
  float iw[4][4];
  {
    const u16* ip = ibuf + (size_t)b * 8388608 + w * 16 + c16;
    #pragma unroll
    for (int rt = 0; rt < 4; ++rt)
      #pragma unroll
      for (int r = 0; r < 4; ++r) {
        const int tok = rt * 16 + g * 4 + r;
        const int hh = (wh * 8 + (tok >> 3) + shift) & 255;
        const int wp = (wn * 8 + (tok & 7) + shift) & 255;
        iw[rt][r] = blo(ip[(size_t)((hh << 8) + wp) * 128]);
      }
  }

  // ---- phase 0: LN1, 8 tokens per wave (once per window)
  {
    float gg[8], bb[8];
    *(float4*)&gg[0] = *(const float4*)(g1 + c8);
    *(float4*)&gg[4] = *(const float4*)(g1 + c8 + 4);
    *(float4*)&bb[0] = *(const float4*)(b1 + c8);
    *(float4*)&bb[4] = *(const float4*)(b1 + c8 + 4);
    #pragma unroll
    for (int s = 0; s < 2; ++s) {
      const int tok = w * 8 + s * 4 + g;
      const int hh = (wh * 8 + (tok >> 3) + shift) & 255;
      const int wp = (wn * 8 + (tok & 7) + shift) & 255;
      const float* xr = xbuf + (size_t)((b * 256 + hh) * 256 + wp) * 128 + c8;
      float v[8];
      *(float4*)&v[0] = *(const float4*)xr;
      *(float4*)&v[4] = *(const float4*)(xr + 4);
      float sm = 0.f, sq = 0.f;
      #pragma unroll
      for (int j = 0; j < 8; ++j) { sm += v[j]; sq = fmaf(v[j], v[j], sq); }
      #pragma unroll
      for (int o = 8; o; o >>= 1) { sm += __shfl_xor(sm, o); sq += __shfl_xor(sq, o); }
      const float mean = sm * 0.0078125f;
      const float rstd = rsqrtf(fmaf(-mean, mean, sq * 0.0078125f) + 1e-5f);
      unsigned pk[4];
      #pragma unroll
      for (int jj = 0; jj < 4; ++jj) {
        const float o0 = (v[2 * jj] - mean) * rstd * gg[2 * jj] + bb[2 * jj];
        const float o1 = (v[2 * jj + 1] - mean) * rstd * gg[2 * jj + 1] + bb[2 * jj + 1];
        pk[jj] = f2b_pk(o0, o1);
      }
      i32x4 st; st[0] = (int)pk[0]; st[1] = (int)pk[1]; st[2] = (int)pk[2]; st[3] = (int)pk[3];
      *(i32x4*)&xn[(tok * 128 + c8) ^ ((tok & 7) << 3)] = st;
    }
  }
  __syncthreads();

  // ---- phase 1a: V GEMM (frees iw), modulate, stage to own QV chunk, read vb
  bfrag vb[2];
  {
    const int colv = (16 + w) * 16 + c16;
    const float bv = qb[colv];
    f32x4 acv[4];
    #pragma unroll
    for (int rt = 0; rt < 4; ++rt) acv[rt] = (f32x4){bv, bv, bv, bv};
    const u16* bp = qwl + colv * 128 + g * 8;
    __builtin_amdgcn_s_setprio(1);
    #pragma unroll
    for (int kt = 0; kt < 4; ++kt) {
      const bfrag bw = *(const bfrag*)(bp + kt * 32);
      #pragma unroll
      for (int rt = 0; rt < 4; ++rt) {
        const bfrag a = *(const bfrag*)&xn[xn_addr(rt * 16 + c16, kt * 4 + g)];
        acv[rt] = mfma16(a, bw, acv[rt]);
      }
    }
    __builtin_amdgcn_s_setprio(0);
    u16* vt = QV + w * 1024 + c16 * 64;
    const int sx = (c16 & 7) << 3;
    #pragma unroll
    for (int rt = 0; rt < 4; ++rt) {
      const unsigned p0 = f2b_pk(acv[rt][0] * iw[rt][0], acv[rt][1] * iw[rt][1]);
      const unsigned p1 = f2b_pk(acv[rt][2] * iw[rt][2], acv[rt][3] * iw[rt][3]);
      i32x2 pp; pp[0] = (int)p0; pp[1] = (int)p1;
      *(i32x2*)&vt[(rt * 16 + g * 4) ^ sx] = pp;
    }
    // own-wave readback (compiler orders LDS ops on aliasing pointers)
    #pragma unroll
    for (int kt = 0; kt < 2; ++kt)
      vb[kt] = *(const bfrag*)&QV[w * 1024 + c16 * 64 + ((kt * 32 + g * 8) ^ sx)];
  }

  // ---- phase 1b: Q GEMM -> own QV chunk (overwrites V staging; vb already in regs)
  {
    const int colq = w * 16 + c16;
    const float bq = qb[colq];
    f32x4 acq[4];
    #pragma unroll
    for (int rt = 0; rt < 4; ++rt) acq[rt] = (f32x4){bq, bq, bq, bq};
    const u16* bpq = qwl + colq * 128 + g * 8;
    __builtin_amdgcn_s_setprio(1);
    #pragma unroll
    for (int kt = 0; kt < 4; ++kt) {
      const bfrag bwq = *(const bfrag*)(bpq + kt * 32);
      #pragma unroll
      for (int rt = 0; rt < 4; ++rt) {
        const bfrag a = *(const bfrag*)&xn[xn_addr(rt * 16 + c16, kt * 4 + g)];
        acq[rt] = mfma16(a, bwq, acq[rt]);
      }
    }
    __builtin_amdgcn_s_setprio(0);
    u16* dq = QV + w * 1024 + ((c16 >> 3) * 64) * 8 + (c16 & 7);
    #pragma unroll
    for (int rt = 0; rt < 4; ++rt)
      #pragma unroll
      for (int r = 0; r < 4; ++r)
        dq[(rt * 16 + g * 4 + r) * 8] = f2b(acq[rt][r]);
  }

  // ---- phase 1c: K GEMM -> own K2 chunk, read kf
  const bfrag zfrag = {0, 0, 0, 0, 0, 0, 0, 0};
  const f32x4 zacc = {0.f, 0.f, 0.f, 0.f};
  bfrag kf[4];
  {
    const int colk = 128 + w * 16 + c16;
    const float bk = qb[colk];
    f32x4 ack[4];
    #pragma unroll
    for (int rt = 0; rt < 4; ++rt) ack[rt] = (f32x4){bk, bk, bk, bk};
    const u16* bpk = qwl + colk * 128 + g * 8;
    __builtin_amdgcn_s_setprio(1);
    #pragma unroll
    for (int kt = 0; kt < 4; ++kt) {
      const bfrag bwk = *(const bfrag*)(bpk + kt * 32);
      #pragma unroll
      for (int rt = 0; rt < 4; ++rt) {
        const bfrag a = *(const bfrag*)&xn[xn_addr(rt * 16 + c16, kt * 4 + g)];
        ack[rt] = mfma16(a, bwk, ack[rt]);
      }
    }
    __builtin_amdgcn_s_setprio(0);
    u16* dk = K2 + w * 1024 + ((c16 >> 3) * 64) * 8 + (c16 & 7);
    #pragma unroll
    for (int rt = 0; rt < 4; ++rt)
      #pragma unroll
      for (int r = 0; r < 4; ++r)
        dk[(rt * 16 + g * 4 + r) * 8] = f2b(ack[rt][r]);
    #pragma unroll
    for (int jt = 0; jt < 4; ++jt) {
      bfrag v = zfrag;
      if (l < 32) v = *(const bfrag*)&K2[w * 1024 + (g * 64 + jt * 16 + c16) * 8];
      kf[jt] = v;
    }
  }
  __syncthreads();   // all xn reads done; xn region may now become O

  // ---- phases 2+3 fused per 16-row block: S -> softmax -> PV -> O(LDS)
  const float* bl2 = biasb + blk * 32768 + w * 4096;
  const bool mk = (shift > 0) && ((wh == 31) || (wn == 31));
  int lj[4];
  if (mk) {
    #pragma unroll
    for (int jt = 0; jt < 4; ++jt) {
      const int j = jt * 16 + c16;
      lj[jt] = ((wh == 31) ? (((j >> 3) < 4) ? 1 : 2) : 0) * 3 +
               ((wn == 31) ? (((j & 7) < 4) ? 1 : 2) : 0);
    }
  }
  u16* Pw = K2 + w * 1024;   // kf in regs (all waves, pre-barrier); K2 becomes P scratch

  #pragma unroll
  for (int it = 0; it < 4; ++it) {
    bfrag qf = zfrag;
    if (l < 32) qf = *(const bfrag*)&QV[w * 1024 + (g * 64 + it * 16 + c16) * 8];
    f32x4 s4[4];
    __builtin_amdgcn_s_setprio(1);
    #pragma unroll
    for (int jt = 0; jt < 4; ++jt) s4[jt] = mfma16(qf, kf[jt], zacc);
    __builtin_amdgcn_s_setprio(0);

    #pragma unroll
    for (int jt = 0; jt < 4; ++jt) {
      const float4 bv4 = *(const float4*)&bl2[(jt * 16 + c16) * 64 + it * 16 + g * 4];
      #pragma unroll
      for (int r = 0; r < 4; ++r)
        s4[jt][r] = fmaf(s4[jt][r], 0.25f, (&bv4.x)[r]);
    }
    if (mk) {
      #pragma unroll
      for (int r = 0; r < 4; ++r) {
        const int i = it * 16 + g * 4 + r;
        const int li = ((wh == 31) ? (((i >> 3) < 4) ? 1 : 2) : 0) * 3 +
                       ((wn == 31) ? (((i & 7) < 4) ? 1 : 2) : 0);
        #pragma unroll
        for (int jt = 0; jt < 4; ++jt)
          if (li != lj[jt]) s4[jt][r] = -1e30f;
      }
    }

    #pragma unroll
    for (int r = 0; r < 4; ++r) {
      float mx = fmaxf(fmaxf(s4[0][r], s4[1][r]), fmaxf(s4[2][r], s4[3][r]));
      #pragma unroll
      for (int o = 8; o; o >>= 1) mx = fmaxf(mx, __shfl_xor(mx, o));
      float e0 = __expf(s4[0][r] - mx);
      float e1 = __expf(s4[1][r] - mx);
      float e2 = __expf(s4[2][r] - mx);
      float e3 = __expf(s4[3][r] - mx);
      float sm = e0 + e1 + e2 + e3;
      #pragma unroll
      for (int o = 8; o; o >>= 1) sm += __shfl_xor(sm, o);
      const float inv = 1.0f / sm;
      s4[0][r] = e0 * inv; s4[1][r] = e1 * inv;
      s4[2][r] = e2 * inv; s4[3][r] = e3 * inv;
    }

    #pragma unroll
    for (int jt = 0; jt < 4; ++jt)
      #pragma unroll
      for (int r = 0; r < 4; ++r)
        Pw[(g * 4 + r) * 40 + jt * 16 + c16] = f2b(s4[jt][r]);
    const bfrag pa0 = *(const bfrag*)&Pw[c16 * 40 + g * 8];
    const bfrag pa1 = *(const bfrag*)&Pw[c16 * 40 + 32 + g * 8];
    f32x4 o = zacc;
    __builtin_amdgcn_s_setprio(1);
    o = mfma16(pa0, vb[0], o);
    o = mfma16(pa1, vb[1], o);
    __builtin_amdgcn_s_setprio(0);
    // O[tok][col] swizzled like xn; col = w*16 + c16
    #pragma unroll
    for (int r = 0; r < 4; ++r) {
      const int tok = it * 16 + g * 4 + r;
      O[tok * 128 + (((w * 2 + (c16 >> 3)) ^ (tok & 7)) << 3) + (c16 & 7)] = f2b(o[r]);
    }
  }
  __syncthreads();   // O fully staged

  // ---- phase 4: proj GEMM + residual. wave w: row-tile (w&3), col-half (w>>2)
  {
    const int prt = w & 3, ph = w >> 2;
    bfrag af[4];
    #pragma unroll
    for (int kt = 0; kt < 4; ++kt)
      af[kt] = *(const bfrag*)&O[xn_addr(prt * 16 + c16, kt * 4 + g)];
    const u16* pwl = pwT + blk * 16384;
    const float* pb = wsf + OFF_PB + blk * 128;
    #pragma unroll
    for (int ct = 0; ct < 4; ++ct) {
      const int col = ph * 64 + ct * 16 + c16;
      const float bv = pb[col];
      f32x4 ac = {bv, bv, bv, bv};
      const u16* bp = pwl + col * 128 + g * 8;
      __builtin_amdgcn_s_setprio(1);
      #pragma unroll
      for (int kt = 0; kt < 4; ++kt) ac = mfma16(af[kt], *(const bfrag*)(bp + kt * 32), ac);
      __builtin_amdgcn_s_setprio(0);
      #pragma unroll
      for (int r = 0; r < 4; ++r) {
        const int tok = prt * 16 + g * 4 + r;
        const int hh = (wh * 8 + (tok >> 3) + shift) & 255;
        const int wp = (wn * 8 + (tok & 7) + shift) & 255;
        const size_t xi = (size_t)((b * 256 + hh) * 256 + wp) * 128 + col;
        xbuf[xi] += ac[r];
      }
    }
  }
}

// ---------------- fused LN2 + FFN v5d: v5c + swr() hid swizzle ----------------
// (256,3) reg cap verified round-6. swr applied at all 4 hid sites (LN2 store,
// af read, GELU store, a2 read) — targets the 9.7M bank-conflict cycles from the
// GELU scatter (rows r and 8+r aliased under the old ((row&7)<<3) key).
__global__ __launch_bounds__(256, 3) void k_ffn(
    float* xbuf, const float* __restrict__ wsf,
    const u16* __restrict__ f1S, const u16* __restrict__ f2S,
    const int blk, void* __restrict__ outp, const int last,
    const int* __restrict__ flagp)
{
  __shared__ __align__(16) u16 B0[8192];    // 16KB weight tile buf (ping)
  __shared__ __align__(16) u16 B1[8192];    // 16KB weight tile buf (pong)
  __shared__ __align__(16) u16 hid[8192];   // 16KB: 4 waves x [16 rows][128] swr-swz
  __shared__ float sbias[512];              // f1 biases (keeps loop VMEM-clean)
  const int bfl = *flagp;
  const int t = threadIdx.x, l = t & 63, w = t >> 6;
  u16* hw = hid + w * 2048;
  const int pix0 = blockIdx.x * 64;
  const float* g2 = wsf + OFF_N2G + blk * 128;
  const float* b2 = wsf + OFF_N2B + blk * 128;
  const float* f1bp = wsf + OFF_F1B + blk * 512;
  const float* f2bp = wsf + OFF_F2B + blk * 128;
  const u16* f1 = f1S + (size_t)blk * 65536;
  const u16* f2 = f2S + (size_t)blk * 65536;

  auto STAGE = [&](const u16* src, u16* dstbuf) {
    const u16* gp = src + w * 2048 + l * 8;
    u16* d = dstbuf + w * 2048;
    #pragma unroll
    for (int q = 0; q < 4; ++q)
      __builtin_amdgcn_global_load_lds(gp + q * 512, d + q * 512, 16, 0, 0);
  };
  auto tsrc = [&](int i) -> const u16* {
    const int cc = i >> 2, pp = i & 3;
    return (pp < 2 ? f1 : f2) + cc * 16384 + (pp & 1) * 8192;
  };

  STAGE(tsrc(0), B0);
  sbias[t] = f1bp[t];
  sbias[t + 256] = f1bp[t + 256];

  {
    const int g = l >> 4, c16 = l & 15, c8 = c16 * 8;
    float gg[8], bb[8];
    *(float4*)&gg[0] = *(const float4*)(g2 + c8);
    *(float4*)&gg[4] = *(const float4*)(g2 + c8 + 4);
    *(float4*)&bb[0] = *(const float4*)(b2 + c8);
    *(float4*)&bb[4] = *(const float4*)(b2 + c8 + 4);
    #pragma unroll
    for (int s = 0; s < 4; ++s) {
      const int tt = s * 4 + g;
      const float* xr = xbuf + (size_t)(pix0 + w * 16 + tt) * 128 + c8;
      float v[8];
      *(float4*)&v[0] = *(const float4*)xr;
      *(float4*)&v[4] = *(const float4*)(xr + 4);
      float sm = 0.f, sq = 0.f;
      #pragma unroll
      for (int j = 0; j < 8; ++j) { sm += v[j]; sq = fmaf(v[j], v[j], sq); }
      #pragma unroll
      for (int o = 8; o; o >>= 1) { sm += __shfl_xor(sm, o); sq += __shfl_xor(sq, o); }
      const float mean = sm * 0.0078125f;
      const float rstd = rsqrtf(fmaf(-mean, mean, sq * 0.0078125f) + 1e-5f);
      unsigned pk[4];
      #pragma unroll
      for (int jj = 0; jj < 4; ++jj) {
        const float o0 = (v[2 * jj] - mean) * rstd * gg[2 * jj] + bb[2 * jj];
        const float o1 = (v[2 * jj + 1] - mean) * rstd * gg[2 * jj + 1] + bb[2 * jj + 1];
        pk[jj] = f2b_pk(o0, o1);
      }
      i32x4 st; st[0] = (int)pk[0]; st[1] = (int)pk[1]; st[2] = (int)pk[2]; st[3] = (int)pk[3];
      *(i32x4*)&hw[(tt * 128 + c8) ^ swr(tt)] = st;
    }
  }
  bfrag af[4];
  #pragma unroll
  for (int kt = 0; kt < 4; ++kt)
    af[kt] = *(const bfrag*)&hw[((l & 15) * 128 + kt * 32 + (l >> 4) * 8) ^ swr(l & 15)];

  f32x4 y[8];
  #pragma unroll
  for (int ct = 0; ct < 8; ++ct) {
    const float bv = f2bp[ct * 16 + (l & 15)];
    y[ct] = (f32x4){bv, bv, bv, bv};
  }

  for (int c = 0; c < 4; ++c) {
    #pragma unroll
    for (int p = 0; p < 4; ++p) {
      const int i = c * 4 + p;
      if (i < 15) STAGE(tsrc(i + 1), (i & 1) ? B0 : B1);
      if (i == 0) asm volatile("s_waitcnt vmcnt(4) lgkmcnt(0)" ::: "memory");
      else if (i < 15) asm volatile("s_waitcnt vmcnt(4)" ::: "memory");
      else asm volatile("s_waitcnt vmcnt(0)" ::: "memory");
      __builtin_amdgcn_sched_barrier(0);
      __builtin_amdgcn_s_barrier();
      const u16* BUF = (i & 1) ? B1 : B0;
      if (p < 2) {
        #pragma unroll
        for (int c1 = 0; c1 < 4; ++c1) {
          const int wcol = c1 * 16 + (l & 15);
          const int n = p * 64 + wcol;
          const float bv = sbias[c * 128 + n];
          f32x4 a1 = {bv, bv, bv, bv};
          #pragma unroll
          for (int kt = 0; kt < 4; ++kt) {
            const bfrag bw = *(const bfrag*)&BUF[(wcol * 128 + kt * 32 + (l >> 4) * 8) ^ ((wcol & 7) << 3)];
            a1 = mfma16(af[kt], bw, a1);
          }
          #pragma unroll
          for (int r = 0; r < 4; ++r) {
            const int row = (l >> 4) * 4 + r;
            hw[(row * 128 + n) ^ swr(row)] = f2b(fast_gelu(a1[r]));
          }
        }
      } else {
        const int kh = p - 2;
        bfrag a2[2];
        #pragma unroll
        for (int kt = 0; kt < 2; ++kt)
          a2[kt] = *(const bfrag*)&hw[((l & 15) * 128 + kh * 64 + kt * 32 + (l >> 4) * 8) ^ swr(l & 15)];
        #pragma unroll
        for (int ct = 0; ct < 8; ++ct) {
          const int col = ct * 16 + (l & 15);
          #pragma unroll
          for (int kt = 0; kt < 2; ++kt) {
            const bfrag bw = *(const bfrag*)&BUF[(col * 64 + kt * 32 + (l >> 4) * 8) ^ ((col & 7) << 3)];
            y[ct] = mfma16(a2[kt], bw, y[ct]);
          }
        }
      }
      __builtin_amdgcn_s_barrier();
    }
  }

  #pragma unroll
  for (int ct = 0; ct < 8; ++ct)
    #pragma unroll
    for (int r = 0; r < 4; ++r) {
      const int tok = w * 16 + (l >> 4) * 4 + r;
      const int pix = pix0 + tok;
      const int col = ct * 16 + (l & 15);
      const float rv = xbuf[(size_t)pix * 128 + col] + y[ct][r];
      if (last) {
        const int wp = pix & 255, hh2 = (pix >> 8) & 255, bb = pix >> 16;
        const long oi = (((long)bb * 128 + col) * 256 + hh2) * 256 + wp;
        if (bfl) ((u16*)outp)[oi] = f2b(rv);
        else ((float*)outp)[oi] = rv;
      } else {
        xbuf[(size_t)pix * 128 + col] = rv;
      }
    }
}

extern "C" void kernel_launch(void* const* d_in, const int* in_sizes, int n_in,
                              void* d_out, int out_size, void* d_ws, size_t ws_size,
                              hipStream_t stream) {
  (void)in_sizes; (void)n_in; (void)out_size; (void)ws_size;
  float* wsf = (float*)d_ws;
  int* flag = (int*)d_ws;
  const void* x = d_in[0];
  const void* illu = d_in[1];

  k_sniff<<<1, 256, 0, stream>>>((const u16*)x, flag);

  static const int cv_idx[8] = {2, 3, 5, 8, 9, 10, 12, 14};
  static const int cv_off[8] = {OFF_N1G, OFF_N1B, OFF_QKVB, OFF_PB, OFF_N2G, OFF_N2B, OFF_F1B, OFF_F2B};
  static const int cv_n[8] = {256, 256, 768, 256, 256, 256, 1024, 256};
  for (int i = 0; i < 8; ++i)
    k_convert<<<(cv_n[i] + 255) / 256, 256, 0, stream>>>(d_in[cv_idx[i]], wsf + cv_off[i], cv_n[i], flag);

  u16* qwT = (u16*)(wsf + OFF_QWT);
  u16* pwT = (u16*)(wsf + OFF_PWT);
  u16* f1wS = (u16*)(wsf + OFF_F1WT);
  u16* f2wS = (u16*)(wsf + OFF_F2WT);
  k_cvtT<<<384, 256, 0, stream>>>(d_in[4], qwT, 128, 384, flag);
  k_cvtT<<<128, 256, 0, stream>>>(d_in[7], pwT, 128, 128, flag);
  k_cvtF1<<<512, 256, 0, stream>>>(d_in[11], f1wS, flag);
  k_cvtF2<<<512, 256, 0, stream>>>(d_in[13], f2wS, flag);
  k_bias<<<256, 256, 0, stream>>>(d_in[6], wsf + OFF_BIAS, flag);

  float* xbuf = wsf + OFF_XBUF;
  u16* ibuf = (u16*)(wsf + OFF_IBUF);
  k_tin<<<8192, 256, 0, stream>>>(x, illu, xbuf, ibuf, flag);

  for (int blk = 0; blk < 2; ++blk) {
    const int shift = blk ? 4 : 0;
    k_attnP<<<4096, 512, 0, stream>>>(xbuf, ibuf, wsf, qwT, pwT, wsf + OFF_BIAS, blk, shift);
    k_ffn<<<4096, 256, 0, stream>>>(xbuf, wsf, f1wS, f2wS, blk, d_out, blk == 1 ? 1 : 0, flag);
  }
}

// Round 10
// 980.016 us; speedup vs baseline: 1.0255x; 1.0082x over previous
//
#include <hip/hip_runtime.h>
#include <hip/hip_bf16.h>

typedef unsigned short u16;
typedef __attribute__((ext_vector_type(8))) short bfrag;   // 8 bf16 = 4 VGPR
typedef __attribute__((ext_vector_type(4))) float f32x4;
typedef __attribute__((ext_vector_type(2))) int i32x2;
typedef __attribute__((ext_vector_type(4))) int i32x4;

// ---------------- ws float-offset layout ----------------
constexpr int OFF_N1G  = 64;                    // int flag at float[0]
constexpr int OFF_N1B  = OFF_N1G + 256;         // 320
constexpr int OFF_QKVB = OFF_N1B + 256;         // 576  (768)
constexpr int OFF_PB   = OFF_QKVB + 768;        // 1344 (256)
constexpr int OFF_N2G  = OFF_PB + 256;          // 1600
constexpr int OFF_N2B  = OFF_N2G + 256;         // 1856
constexpr int OFF_F1B  = OFF_N2B + 256;         // 2112 (1024)
constexpr int OFF_F2B  = OFF_F1B + 1024;        // 3136 (256)
constexpr int OFF_BIAS = OFF_F2B + 256;         // 3392  (+65536 -> 68928)
constexpr int OFF_QWT  = OFF_BIAS + 65536;      // 68928 (+49152 -> 118080)
constexpr int OFF_PWT  = OFF_QWT + 49152;       // 118080 (+16384 -> 134464)
constexpr int OFF_F1WT = OFF_PWT + 16384;       // 134464 (+65536 -> 200000)
constexpr int OFF_F2WT = OFF_F1WT + 65536;      // 200000 (+65536 -> 265536)
constexpr long OFF_XBUF = 265728;               // 256-aligned
constexpr long OFF_IBUF = OFF_XBUF + 33554432;  // xbuf = 33.55M floats; ibuf = 33.55M u16

__device__ __forceinline__ float blo(unsigned w) { return __uint_as_float(w << 16); }
__device__ __forceinline__ u16 f2b(float f) {
  unsigned u = __float_as_uint(f);
  u += 0x7fffu + ((u >> 16) & 1u);
  return (u16)(u >> 16);
}
// packed RNE f32x2 -> bf16x2 (lo = a, hi = b)
__device__ __forceinline__ unsigned f2b_pk(float a, float b) {
  unsigned r;
  asm("v_cvt_pk_bf16_f32 %0, %1, %2" : "=v"(r) : "v"(a), "v"(b));
  return r;
}
__device__ __forceinline__ float ldin(const void* p, long i, int bf) {
  if (bf) return blo((unsigned)((const u16*)p)[i]);
  return ((const float*)p)[i];
}
__device__ __forceinline__ f32x4 mfma16(bfrag a, bfrag b, f32x4 c) {
  return __builtin_amdgcn_mfma_f32_16x16x32_bf16(a, b, c, 0, 0, 0);
}
// hid row swizzle: GELU scatter rows {r,4+r,8+r,12+r} need 4 distinct bank-group
// keys; swr gives them (old ((row&7)<<3) aliased rows r and 8+r -> 4-way).
__device__ __forceinline__ int swr(int row) {
  return ((row & 7) ^ ((row >> 3) << 1)) << 3;
}
// GELU with Abramowitz-Stegun 7.1.26 erf (|err| <= 1.5e-7, far below bf16 ulp)
__device__ __forceinline__ float fast_gelu(float x) {
  const float z = fabsf(x) * 0.70710678118f;
  const float tt = __builtin_amdgcn_rcpf(1.0f + 0.3275911f * z);
  const float poly = tt * (0.254829592f + tt * (-0.284496736f + tt * (1.421413741f +
                     tt * (-1.453152027f + tt * 1.061405429f))));
  const float erfz = 1.0f - poly * __expf(-z * z);
  return x * 0.5f * (1.0f + copysignf(erfz, x));
}

// ---------------- dtype sniff ----------------
__global__ void k_sniff(const u16* __restrict__ x, int* __restrict__ flag) {
  __shared__ int sc[4];
  const int t = threadIdx.x;
  int c = 0;
  for (int i = t; i < 4096; i += 256) {
    const int e = (x[2 * i] >> 7) & 0xFF;
    c += (e >= 96 && e <= 143) ? 1 : 0;
  }
  #pragma unroll
  for (int o = 32; o; o >>= 1) c += __shfl_down(c, o);
  if ((t & 63) == 0) sc[t >> 6] = c;
  __syncthreads();
  if (t == 0) *flag = ((sc[0] + sc[1] + sc[2] + sc[3]) > 2400) ? 1 : 0;
}

// ---------------- small f32 param convert ----------------
__global__ void k_convert(const void* __restrict__ src, float* __restrict__ dst, int n,
                          const int* __restrict__ flagp) {
  const int bf = *flagp;
  const int i = blockIdx.x * 256 + threadIdx.x;
  if (i < n) dst[i] = ldin(src, i, bf);
}

// ---------------- transposed bf16 weight convert: dst[l][n][k] = src[l][k][n] ----------------
__global__ void k_cvtT(const void* __restrict__ src, u16* __restrict__ dst, int K, int N,
                       const int* __restrict__ flagp) {
  const int bf = *flagp;
  const int id = blockIdx.x * 256 + threadIdx.x;
  const int KN = K * N;
  if (id >= 2 * KN) return;
  const int l = id / KN, r = id % KN;
  const int n = r % N, k = r / N;
  const float v = ldin(src, (long)l * KN + (long)k * N + n, bf);
  dst[((long)l * N + n) * K + k] = f2b(v);
}

// ---------------- FFN weight converts: 16KB-tile-contiguous + XOR-pre-swizzled ----------------
// f1: src [l][k=128][n=512] -> tile (n>>6): [64 cols][128 k], idx^((n&7)<<3)
__global__ void k_cvtF1(const void* __restrict__ src, u16* __restrict__ dst,
                        const int* __restrict__ flagp) {
  const int bf = *flagp;
  const int id = blockIdx.x * 256 + threadIdx.x;   // 2*65536
  const int l = id >> 16, r = id & 65535;
  const int k = r >> 9, n = r & 511;
  const float v = ldin(src, (long)l * 65536 + k * 512 + n, bf);
  dst[(long)l * 65536 + (n >> 6) * 8192 + (((n & 63) * 128 + k) ^ ((n & 7) << 3))] = f2b(v);
}
// f2: src [l][k=512][n=128] -> tile (k>>6): [128 cols][64 k], idx^((n&7)<<3)
__global__ void k_cvtF2(const void* __restrict__ src, u16* __restrict__ dst,
                        const int* __restrict__ flagp) {
  const int bf = *flagp;
  const int id = blockIdx.x * 256 + threadIdx.x;   // 2*65536
  const int l = id >> 16, r = id & 65535;
  const int k = r >> 7, n = r & 127;
  const float v = ldin(src, (long)l * 65536 + k * 128 + n, bf);
  dst[(long)l * 65536 + (k >> 6) * 8192 + ((n * 64 + (k & 63)) ^ ((n & 7) << 3))] = f2b(v);
}

// ---------------- relative-position bias table: TRANSPOSED [l][h][j][i] ----------------
__global__ void k_bias(const void* __restrict__ tbl, float* __restrict__ dst,
                       const int* __restrict__ flagp) {
  const int bf = *flagp;
  const int id = blockIdx.x * 256 + threadIdx.x;  // 2*8*64*64
  const int j = id & 63, i = (id >> 6) & 63;
  const int idx = ((i >> 3) - (j >> 3) + 7) * 15 + ((i & 7) - (j & 7) + 7);
  const int h = (id >> 12) & 7, l = id >> 15;
  dst[(id & ~4095) + j * 64 + i] = ldin(tbl, (long)l * 1800 + idx * 8 + h, bf);
}

// ---------------- x: (B,C,H,W) -> (B,H,W,C) f32  AND  illu -> (B,H,W,C) bf16 ----------------
__global__ __launch_bounds__(256) void k_tin(const void* __restrict__ src,
                                             const void* __restrict__ il,
                                             float* __restrict__ dst,
                                             u16* __restrict__ idst,
                                             const int* __restrict__ flagp) {
  __shared__ float tile[64][65];
  const int bf = *flagp;
  const int bid = blockIdx.x;     // B*H*4*2 = 8192
  const int cb = bid & 1, wb = (bid >> 1) & 3, h = (bid >> 3) & 255, b = bid >> 11;
  const int tw = threadIdx.x & 63, tg = threadIdx.x >> 6;
  #pragma unroll
  for (int i = 0; i < 16; ++i) {
    const int c = i * 4 + tg;
    tile[c][tw] = ldin(src, ((long)((b * 128 + cb * 64 + c) * 256 + h)) * 256 + wb * 64 + tw, bf);
  }
  __syncthreads();
  #pragma unroll
  for (int i = 0; i < 16; ++i) {
    const int wl = i * 4 + tg;
    const int pix = (b * 256 + h) * 256 + wb * 64 + wl;
    dst[(size_t)pix * 128 + cb * 64 + tw] = tile[tw][wl];
  }
  __syncthreads();
  #pragma unroll
  for (int i = 0; i < 16; ++i) {
    const int c = i * 4 + tg;
    tile[c][tw] = ldin(il, ((long)((b * 128 + cb * 64 + c) * 256 + h)) * 256 + wb * 64 + tw, bf);
  }
  __syncthreads();
  #pragma unroll
  for (int i = 0; i < 16; ++i) {
    const int wl = i * 4 + tg;
    const int pix = (b * 256 + h) * 256 + wb * 64 + wl;
    idst[(size_t)pix * 128 + cb * 64 + tw] = f2b(tile[tw][wl]);
  }
}

// xn swizzled address: token row of 128 bf16, 16B chunks XOR'd by token
__device__ __forceinline__ int xn_addr(int tok, int chunk) {
  return tok * 128 + ((chunk ^ (tok & 7)) << 3);
}

// ---------------- fused LN1 + qkv + attention + proj + residual (whole window) --------------
// grid 4096 windows, 512 threads = 8 waves = 8 heads. Round-7-proven 64KB layout,
// NO setprio (m190: hurts lockstep GEMM; round-9 A/B confirmed −10us).
// NEW: V+Q+K GEMMs fused into ONE kt-loop with 3 acc sets — xn fragments read
// once (16 b128/wave) instead of 3x (48). GEMM phase was LDS-read-bound.
// (512,4): 128-total-reg cap, 2 blocks/CU. Live peak ~110 (48 acc + iw 16 + af 16
// + addressing) — fits; tripwire: WRITE >> 150MB = spill -> revert fusion.
__global__ __launch_bounds__(512, 4) void k_attnP(
    float* xbuf, const u16* __restrict__ ibuf,
    const float* __restrict__ wsf,
    const u16* __restrict__ qwT, const u16* __restrict__ pwT,
    const float* __restrict__ biasb, const int blk, const int shift)
{
  __shared__ __align__(16) u16 smem[32768];       // 65536 B
  u16* xn = smem;                  // [64][128] swizzled bf16 (live through GEMMs)
  u16* Q2 = smem + 8192;           // per-wave w*1024
  u16* K2 = smem + 16384;          // per-wave w*1024 (P scratch later)
  u16* VT = smem + 24576;          // per-wave w*1024 (O staging later)
  u16* O  = smem + 24576;          // [64 tok][128 ch] swizzled, overlays VT

  const int t = threadIdx.x, l = t & 63, w = t >> 6;   // w = head = 0..7
  const int win = blockIdx.x;
  const int b = win >> 10, wh = (win >> 5) & 31, wn = win & 31;
  const int g = l >> 4, c16 = l & 15, c8 = c16 * 8;

  const float* g1 = wsf + OFF_N1G + blk * 128;
  const float* b1 = wsf + OFF_N1B + blk * 128;
  const float* qb = wsf + OFF_QKVB + blk * 384;
  const u16* qwl = qwT + (size_t)blk * 49152;

  // ---- illu prefetch for head w (coalesced 16-lane u16 runs)
  float iw[4][4];
  {
    const u16* ip = ibuf + (size_t)b * 8388608 + w * 16 + c16;
    #pragma unroll
    for (int rt = 0; rt < 4; ++rt)
      #pragma unroll
      for (int r = 0; r < 4; ++r) {
        const int tok = rt * 16 + g * 4 + r;
        const int hh = (wh * 8 + (tok >> 3) + shift) & 255;
        const int wp = (wn * 8 + (tok & 7) + shift) & 255;
        iw[rt][r] = blo(ip[(size_t)((hh << 8) + wp) * 128]);
      }
  }

  // ---- phase 0: LN1, 8 tokens per wave (once per window)
  {
    float gg[8], bb[8];
    *(float4*)&gg[0] = *(const float4*)(g1 + c8);
    *(float4*)&gg[4] = *(const float4*)(g1 + c8 + 4);
    *(float4*)&bb[0] = *(const float4*)(b1 + c8);
    *(float4*)&bb[4] = *(const float4*)(b1 + c8 + 4);
    #pragma unroll
    for (int s = 0; s < 2; ++s) {
      const int tok = w * 8 + s * 4 + g;
      const int hh = (wh * 8 + (tok >> 3) + shift) & 255;
      const int wp = (wn * 8 + (tok & 7) + shift) & 255;
      const float* xr = xbuf + (size_t)((b * 256 + hh) * 256 + wp) * 128 + c8;
      float v[8];
      *(float4*)&v[0] = *(const float4*)xr;
      *(float4*)&v[4] = *(const float4*)(xr + 4);
      float sm = 0.f, sq = 0.f;
      #pragma unroll
      for (int j = 0; j < 8; ++j) { sm += v[j]; sq = fmaf(v[j], v[j], sq); }
      #pragma unroll
      for (int o = 8; o; o >>= 1) { sm += __shfl_xor(sm, o); sq += __shfl_xor(sq, o); }
      const float mean = sm * 0.0078125f;
      const float rstd = rsqrtf(fmaf(-mean, mean, sq * 0.0078125f) + 1e-5f);
      unsigned pk[4];
      #pragma unroll
      for (int jj = 0; jj < 4; ++jj) {
        const float o0 = (v[2 * jj] - mean) * rstd * gg[2 * jj] + bb[2 * jj];
        const float o1 = (v[2 * jj + 1] - mean) * rstd * gg[2 * jj + 1] + bb[2 * jj + 1];
        pk[jj] = f2b_pk(o0, o1);
      }
      i32x4 st; st[0] = (int)pk[0]; st[1] = (int)pk[1]; st[2] = (int)pk[2]; st[3] = (int)pk[3];
      *(i32x4*)&xn[(tok * 128 + c8) ^ ((tok & 7) << 3)] = st;
    }
  }
  __syncthreads();

  // ---- phase 1: FUSED Q+K+V GEMMs — one kt-loop, xn fragments read once
  bfrag vb[2];
  {
    const int colq = w * 16 + c16;
    const int colk = colq + 128, colv = colq + 256;
    const float bq = qb[colq], bk = qb[colk], bv = qb[colv];
    f32x4 acq[4], ack[4], acv[4];
    #pragma unroll
    for (int rt = 0; rt < 4; ++rt) {
      acq[rt] = (f32x4){bq, bq, bq, bq};
      ack[rt] = (f32x4){bk, bk, bk, bk};
      acv[rt] = (f32x4){bv, bv, bv, bv};
    }
    const u16* bpq = qwl + colq * 128 + g * 8;
    const u16* bpk = qwl + colk * 128 + g * 8;
    const u16* bpv = qwl + colv * 128 + g * 8;
    #pragma unroll
    for (int kt = 0; kt < 4; ++kt) {
      const bfrag bwq = *(const bfrag*)(bpq + kt * 32);
      const bfrag bwk = *(const bfrag*)(bpk + kt * 32);
      const bfrag bwv = *(const bfrag*)(bpv + kt * 32);
      #pragma unroll
      for (int rt = 0; rt < 4; ++rt) {
        const bfrag a = *(const bfrag*)&xn[xn_addr(rt * 16 + c16, kt * 4 + g)];
        acq[rt] = mfma16(a, bwq, acq[rt]);
        ack[rt] = mfma16(a, bwk, ack[rt]);
        acv[rt] = mfma16(a, bwv, acv[rt]);
      }
    }
    // V: modulate by illu, store to own VT chunk, read back vb (transpose)
    {
      u16* vt = VT + w * 1024 + c16 * 64;
      const int sx = (c16 & 7) << 3;
      #pragma unroll
      for (int rt = 0; rt < 4; ++rt) {
        const unsigned p0 = f2b_pk(acv[rt][0] * iw[rt][0], acv[rt][1] * iw[rt][1]);
        const unsigned p1 = f2b_pk(acv[rt][2] * iw[rt][2], acv[rt][3] * iw[rt][3]);
        i32x2 pp; pp[0] = (int)p0; pp[1] = (int)p1;
        *(i32x2*)&vt[(rt * 16 + g * 4) ^ sx] = pp;
      }
      #pragma unroll
      for (int kt = 0; kt < 2; ++kt)
        vb[kt] = *(const bfrag*)&VT[w * 1024 + c16 * 64 + ((kt * 32 + g * 8) ^ sx)];
    }
    // Q, K stores to own chunks
    u16* dq = Q2 + w * 1024 + ((c16 >> 3) * 64) * 8 + (c16 & 7);
    u16* dk = K2 + w * 1024 + ((c16 >> 3) * 64) * 8 + (c16 & 7);
    #pragma unroll
    for (int rt = 0; rt < 4; ++rt)
      #pragma unroll
      for (int r = 0; r < 4; ++r) {
        const int tok = rt * 16 + g * 4 + r;
        dq[tok * 8] = f2b(acq[rt][r]);
        dk[tok * 8] = f2b(ack[rt][r]);
      }
  }

  // ---- load kf (own K2) into regs
  const bfrag zfrag = {0, 0, 0, 0, 0, 0, 0, 0};
  const f32x4 zacc = {0.f, 0.f, 0.f, 0.f};
  bfrag kf[4];
  #pragma unroll
  for (int jt = 0; jt < 4; ++jt) {
    bfrag v = zfrag;
    if (l < 32) v = *(const bfrag*)&K2[w * 1024 + (g * 64 + jt * 16 + c16) * 8];
    kf[jt] = v;
  }
  __syncthreads();   // all waves hold vb/kf -> VT region may now become O

  // ---- phases 2+3 fused per 16-row block: S -> softmax -> PV -> O(LDS)
  const float* bl2 = biasb + blk * 32768 + w * 4096;
  const bool mk = (shift > 0) && ((wh == 31) || (wn == 31));
  int lj[4];
  if (mk) {
    #pragma unroll
    for (int jt = 0; jt < 4; ++jt) {
      const int j = jt * 16 + c16;
      lj[jt] = ((wh == 31) ? (((j >> 3) < 4) ? 1 : 2) : 0) * 3 +
               ((wn == 31) ? (((j & 7) < 4) ? 1 : 2) : 0);
    }
  }
  u16* Pw = K2 + w * 1024;   // kf in regs; own K2 chunk becomes P scratch

  #pragma unroll
  for (int it = 0; it < 4; ++it) {
    bfrag qf = zfrag;
    if (l < 32) qf = *(const bfrag*)&Q2[w * 1024 + (g * 64 + it * 16 + c16) * 8];
    f32x4 s4[4];
    #pragma unroll
    for (int jt = 0; jt < 4; ++jt) s4[jt] = mfma16(qf, kf[jt], zacc);

    #pragma unroll
    for (int jt = 0; jt < 4; ++jt) {
      const float4 bv4 = *(const float4*)&bl2[(jt * 16 + c16) * 64 + it * 16 + g * 4];
      #pragma unroll
      for (int r = 0; r < 4; ++r)
        s4[jt][r] = fmaf(s4[jt][r], 0.25f, (&bv4.x)[r]);
    }
    if (mk) {
      #pragma unroll
      for (int r = 0; r < 4; ++r) {
        const int i = it * 16 + g * 4 + r;
        const int li = ((wh == 31) ? (((i >> 3) < 4) ? 1 : 2) : 0) * 3 +
                       ((wn == 31) ? (((i & 7) < 4) ? 1 : 2) : 0);
        #pragma unroll
        for (int jt = 0; jt < 4; ++jt)
          if (li != lj[jt]) s4[jt][r] = -1e30f;
      }
    }

    #pragma unroll
    for (int r = 0; r < 4; ++r) {
      float mx = fmaxf(fmaxf(s4[0][r], s4[1][r]), fmaxf(s4[2][r], s4[3][r]));
      #pragma unroll
      for (int o = 8; o; o >>= 1) mx = fmaxf(mx, __shfl_xor(mx, o));
      float e0 = __expf(s4[0][r] - mx);
      float e1 = __expf(s4[1][r] - mx);
      float e2 = __expf(s4[2][r] - mx);
      float e3 = __expf(s4[3][r] - mx);
      float sm = e0 + e1 + e2 + e3;
      #pragma unroll
      for (int o = 8; o; o >>= 1) sm += __shfl_xor(sm, o);
      const float inv = 1.0f / sm;
      s4[0][r] = e0 * inv; s4[1][r] = e1 * inv;
      s4[2][r] = e2 * inv; s4[3][r] = e3 * inv;
    }

    #pragma unroll
    for (int jt = 0; jt < 4; ++jt)
      #pragma unroll
      for (int r = 0; r < 4; ++r)
        Pw[(g * 4 + r) * 40 + jt * 16 + c16] = f2b(s4[jt][r]);
    const bfrag pa0 = *(const bfrag*)&Pw[c16 * 40 + g * 8];
    const bfrag pa1 = *(const bfrag*)&Pw[c16 * 40 + 32 + g * 8];
    f32x4 o = zacc;
    o = mfma16(pa0, vb[0], o);
    o = mfma16(pa1, vb[1], o);
    // O[tok][col] swizzled like xn; col = w*16 + c16
    #pragma unroll
    for (int r = 0; r < 4; ++r) {
      const int tok = it * 16 + g * 4 + r;
      O[tok * 128 + (((w * 2 + (c16 >> 3)) ^ (tok & 7)) << 3) + (c16 & 7)] = f2b(o[r]);
    }
  }
  __syncthreads();   // O fully staged

  // ---- phase 4: proj GEMM + residual. wave w: row-tile (w&3), col-half (w>>2)
  {
    const int prt = w & 3, ph = w >> 2;
    bfrag af[4];
    #pragma unroll
    for (int kt = 0; kt < 4; ++kt)
      af[kt] = *(const bfrag*)&O[xn_addr(prt * 16 + c16, kt * 4 + g)];
    const u16* pwl = pwT + blk * 16384;
    const float* pb = wsf + OFF_PB + blk * 128;
    #pragma unroll
    for (int ct = 0; ct < 4; ++ct) {
      const int col = ph * 64 + ct * 16 + c16;
      const float bv = pb[col];
      f32x4 ac = {bv, bv, bv, bv};
      const u16* bp = pwl + col * 128 + g * 8;
      #pragma unroll
      for (int kt = 0; kt < 4; ++kt) ac = mfma16(af[kt], *(const bfrag*)(bp + kt * 32), ac);
      #pragma unroll
      for (int r = 0; r < 4; ++r) {
        const int tok = prt * 16 + g * 4 + r;
        const int hh = (wh * 8 + (tok >> 3) + shift) & 255;
        const int wp = (wn * 8 + (tok & 7) + shift) & 255;
        const size_t xi = (size_t)((b * 256 + hh) * 256 + wp) * 128 + col;
        xbuf[xi] += ac[r];
      }
    }
  }
}

// ---------------- fused LN2 + FFN v5d: (256,3) + swr hid swizzle (round-9 verified) ----
__global__ __launch_bounds__(256, 3) void k_ffn(
    float* xbuf, const float* __restrict__ wsf,
    const u16* __restrict__ f1S, const u16* __restrict__ f2S,
    const int blk, void* __restrict__ outp, const int last,
    const int* __restrict__ flagp)
{
  __shared__ __align__(16) u16 B0[8192];    // 16KB weight tile buf (ping)
  __shared__ __align__(16) u16 B1[8192];    // 16KB weight tile buf (pong)
  __shared__ __align__(16) u16 hid[8192];   // 16KB: 4 waves x [16 rows][128] swr-swz
  __shared__ float sbias[512];              // f1 biases (keeps loop VMEM-clean)
  const int bfl = *flagp;
  const int t = threadIdx.x, l = t & 63, w = t >> 6;
  u16* hw = hid + w * 2048;
  const int pix0 = blockIdx.x * 64;
  const float* g2 = wsf + OFF_N2G + blk * 128;
  const float* b2 = wsf + OFF_N2B + blk * 128;
  const float* f1bp = wsf + OFF_F1B + blk * 512;
  const float* f2bp = wsf + OFF_F2B + blk * 128;
  const u16* f1 = f1S + (size_t)blk * 65536;
  const u16* f2 = f2S + (size_t)blk * 65536;

  auto STAGE = [&](const u16* src, u16* dstbuf) {
    const u16* gp = src + w * 2048 + l * 8;
    u16* d = dstbuf + w * 2048;
    #pragma unroll
    for (int q = 0; q < 4; ++q)
      __builtin_amdgcn_global_load_lds(gp + q * 512, d + q * 512, 16, 0, 0);
  };
  auto tsrc = [&](int i) -> const u16* {
    const int cc = i >> 2, pp = i & 3;
    return (pp < 2 ? f1 : f2) + cc * 16384 + (pp & 1) * 8192;
  };

  STAGE(tsrc(0), B0);
  sbias[t] = f1bp[t];
  sbias[t + 256] = f1bp[t + 256];

  {
    const int g = l >> 4, c16 = l & 15, c8 = c16 * 8;
    float gg[8], bb[8];
    *(float4*)&gg[0] = *(const float4*)(g2 + c8);
    *(float4*)&gg[4] = *(const float4*)(g2 + c8 + 4);
    *(float4*)&bb[0] = *(const float4*)(b2 + c8);
    *(float4*)&bb[4] = *(const float4*)(b2 + c8 + 4);
    #pragma unroll
    for (int s = 0; s < 4; ++s) {
      const int tt = s * 4 + g;
      const float* xr = xbuf + (size_t)(pix0 + w * 16 + tt) * 128 + c8;
      float v[8];
      *(float4*)&v[0] = *(const float4*)xr;
      *(float4*)&v[4] = *(const float4*)(xr + 4);
      float sm = 0.f, sq = 0.f;
      #pragma unroll
      for (int j = 0; j < 8; ++j) { sm += v[j]; sq = fmaf(v[j], v[j], sq); }
      #pragma unroll
      for (int o = 8; o; o >>= 1) { sm += __shfl_xor(sm, o); sq += __shfl_xor(sq, o); }
      const float mean = sm * 0.0078125f;
      const float rstd = rsqrtf(fmaf(-mean, mean, sq * 0.0078125f) + 1e-5f);
      unsigned pk[4];
      #pragma unroll
      for (int jj = 0; jj < 4; ++jj) {
        const float o0 = (v[2 * jj] - mean) * rstd * gg[2 * jj] + bb[2 * jj];
        const float o1 = (v[2 * jj + 1] - mean) * rstd * gg[2 * jj + 1] + bb[2 * jj + 1];
        pk[jj] = f2b_pk(o0, o1);
      }
      i32x4 st; st[0] = (int)pk[0]; st[1] = (int)pk[1]; st[2] = (int)pk[2]; st[3] = (int)pk[3];
      *(i32x4*)&hw[(tt * 128 + c8) ^ swr(tt)] = st;
    }
  }
  bfrag af[4];
  #pragma unroll
  for (int kt = 0; kt < 4; ++kt)
    af[kt] = *(const bfrag*)&hw[((l & 15) * 128 + kt * 32 + (l >> 4) * 8) ^ swr(l & 15)];

  f32x4 y[8];
  #pragma unroll
  for (int ct = 0; ct < 8; ++ct) {
    const float bv = f2bp[ct * 16 + (l & 15)];
    y[ct] = (f32x4){bv, bv, bv, bv};
  }

  for (int c = 0; c < 4; ++c) {
    #pragma unroll
    for (int p = 0; p < 4; ++p) {
      const int i = c * 4 + p;
      if (i < 15) STAGE(tsrc(i + 1), (i & 1) ? B0 : B1);
      if (i == 0) asm volatile("s_waitcnt vmcnt(4) lgkmcnt(0)" ::: "memory");
      else if (i < 15) asm volatile("s_waitcnt vmcnt(4)" ::: "memory");
      else asm volatile("s_waitcnt vmcnt(0)" ::: "memory");
      __builtin_amdgcn_sched_barrier(0);
      __builtin_amdgcn_s_barrier();
      const u16* BUF = (i & 1) ? B1 : B0;
      if (p < 2) {
        #pragma unroll
        for (int c1 = 0; c1 < 4; ++c1) {
          const int wcol = c1 * 16 + (l & 15);
          const int n = p * 64 + wcol;
          const float bv = sbias[c * 128 + n];
          f32x4 a1 = {bv, bv, bv, bv};
          #pragma unroll
          for (int kt = 0; kt < 4; ++kt) {
            const bfrag bw = *(const bfrag*)&BUF[(wcol * 128 + kt * 32 + (l >> 4) * 8) ^ ((wcol & 7) << 3)];
            a1 = mfma16(af[kt], bw, a1);
          }
          #pragma unroll
          for (int r = 0; r < 4; ++r) {
            const int row = (l >> 4) * 4 + r;
            hw[(row * 128 + n) ^ swr(row)] = f2b(fast_gelu(a1[r]));
          }
        }
      } else {
        const int kh = p - 2;
        bfrag a2[2];
        #pragma unroll
        for (int kt = 0; kt < 2; ++kt)
          a2[kt] = *(const bfrag*)&hw[((l & 15) * 128 + kh * 64 + kt * 32 + (l >> 4) * 8) ^ swr(l & 15)];
        #pragma unroll
        for (int ct = 0; ct < 8; ++ct) {
          const int col = ct * 16 + (l & 15);
          #pragma unroll
          for (int kt = 0; kt < 2; ++kt) {
            const bfrag bw = *(const bfrag*)&BUF[(col * 64 + kt * 32 + (l >> 4) * 8) ^ ((col & 7) << 3)];
            y[ct] = mfma16(a2[kt], bw, y[ct]);
          }
        }
      }
      __builtin_amdgcn_s_barrier();
    }
  }

  #pragma unroll
  for (int ct = 0; ct < 8; ++ct)
    #pragma unroll
    for (int r = 0; r < 4; ++r) {
      const int tok = w * 16 + (l >> 4) * 4 + r;
      const int pix = pix0 + tok;
      const int col = ct * 16 + (l & 15);
      const float rv = xbuf[(size_t)pix * 128 + col] + y[ct][r];
      if (last) {
        const int wp = pix & 255, hh2 = (pix >> 8) & 255, bb = pix >> 16;
        const long oi = (((long)bb * 128 + col) * 256 + hh2) * 256 + wp;
        if (bfl) ((u16*)outp)[oi] = f2b(rv);
        else ((float*)outp)[oi] = rv;
      } else {
        xbuf[(size_t)pix * 128 + col] = rv;
      }
    }
}

extern "C" void kernel_launch(void* const* d_in, const int* in_sizes, int n_in,
                              void* d_out, int out_size, void* d_ws, size_t ws_size,
                              hipStream_t stream) {
  (void)in_sizes; (void)n_in; (void)out_size; (void)ws_size;
  float* wsf = (float*)d_ws;
  int* flag = (int*)d_ws;
  const void* x = d_in[0];
  const void* illu = d_in[1];

  k_sniff<<<1, 256, 0, stream>>>((const u16*)x, flag);

  static const int cv_idx[8] = {2, 3, 5, 8, 9, 10, 12, 14};
  static const int cv_off[8] = {OFF_N1G, OFF_N1B, OFF_QKVB, OFF_PB, OFF_N2G, OFF_N2B, OFF_F1B, OFF_F2B};
  static const int cv_n[8] = {256, 256, 768, 256, 256, 256, 1024, 256};
  for (int i = 0; i < 8; ++i)
    k_convert<<<(cv_n[i] + 255) / 256, 256, 0, stream>>>(d_in[cv_idx[i]], wsf + cv_off[i], cv_n[i], flag);

  u16* qwT = (u16*)(wsf + OFF_QWT);
  u16* pwT = (u16*)(wsf + OFF_PWT);
  u16* f1wS = (u16*)(wsf + OFF_F1WT);
  u16* f2wS = (u16*)(wsf + OFF_F2WT);
  k_cvtT<<<384, 256, 0, stream>>>(d_in[4], qwT, 128, 384, flag);
  k_cvtT<<<128, 256, 0, stream>>>(d_in[7], pwT, 128, 128, flag);
  k_cvtF1<<<512, 256, 0, stream>>>(d_in[11], f1wS, flag);
  k_cvtF2<<<512, 256, 0, stream>>>(d_in[13], f2wS, flag);
  k_bias<<<256, 256, 0, stream>>>(d_in[6], wsf + OFF_BIAS, flag);

  float* xbuf = wsf + OFF_XBUF;
  u16* ibuf = (u16*)(wsf + OFF_IBUF);
  k_tin<<<8192, 256, 0, stream>>>(x, illu, xbuf, ibuf, flag);

  for (int blk = 0; blk < 2; ++blk) {
    const int shift = blk ? 4 : 0;
    k_attnP<<<4096, 512, 0, stream>>>(xbuf, ibuf, wsf, qwT, pwT, wsf + OFF_BIAS, blk, shift);
    k_ffn<<<4096, 256, 0, stream>>>(xbuf, wsf, f1wS, f2wS, blk, d_out, blk == 1 ? 1 : 0, flag);
  }
}